// Round 18
// baseline (340.771 us; speedup 1.0000x reference)
//
#include <hip/hip_runtime.h>

// Transformer block. Round 17: attn pass-merge — the pair's two q-tiles
// share one kt loop and one K/V staging stream (ranges overlap on [0,ntA)):
// K/V HBM traffic and barrier count drop ~25%, dual-tile iterations amortize
// sync. Compute per block unchanged; numerics identical. Everything else
// frozen (QKV 256x192 3-phase, FFN1 256^2 4-phase, proj/FFN2 128^2 ring,
// prep+LN1 fused, LN2 standalone).
//
// Workspace (~136 MiB): [Q|K|Vt|att] <- ffh overlay; [h1b][x2][weights][bqkv]

constexpr int Bb = 4, Tt = 2048, Cc = 1024, Hh = 16, HSz = 64, Ff = 4096;
constexpr int Mrows = Bb * Tt;  // 8192

typedef __attribute__((ext_vector_type(8))) short bf16x8;
typedef __attribute__((ext_vector_type(4))) float f32x4;

__device__ __forceinline__ ushort f2bf(float f) {
  uint u = __builtin_bit_cast(uint, f);
  uint r = (u + 0x7fffu + ((u >> 16) & 1u)) >> 16;
  return (ushort)r;
}
__device__ __forceinline__ float bf2f(ushort s) {
  return __builtin_bit_cast(float, ((uint)s) << 16);
}
__device__ __forceinline__ uint cvtpk_bf16(float lo, float hi) {
  uint r;
  asm("v_cvt_pk_bf16_f32 %0, %1, %2" : "=v"(r) : "v"(lo), "v"(hi));
  return r;
}
__device__ __forceinline__ void gload16(const void* g, void* l) {
  __builtin_amdgcn_global_load_lds(
      (const __attribute__((address_space(1))) void*)g,
      (__attribute__((address_space(3))) void*)l, 16, 0, 0);
}
#define VMCNT(n) asm volatile("s_waitcnt vmcnt(" #n ")" ::: "memory")
#define LGKM0                                          \
  do {                                                 \
    asm volatile("s_waitcnt lgkmcnt(0)" ::: "memory"); \
    __builtin_amdgcn_sched_barrier(0);                 \
  } while (0)
#define BARRIER __builtin_amdgcn_s_barrier()

// ---------------- LayerNorm body: fp32 in, bf16 out ----------------
__device__ __forceinline__ void ln_body(const float* __restrict__ x,
                                        const float* __restrict__ g,
                                        const float* __restrict__ b,
                                        ushort* __restrict__ out, int row) {
  const float* xr = x + (size_t)row * Cc;
  int c4 = threadIdx.x * 4;
  float4 v = *(const float4*)(xr + c4);
  float s1 = v.x + v.y + v.z + v.w;
  float s2 = v.x * v.x + v.y * v.y + v.z * v.z + v.w * v.w;
#pragma unroll
  for (int off = 32; off >= 1; off >>= 1) {
    s1 += __shfl_xor(s1, off);
    s2 += __shfl_xor(s2, off);
  }
  __shared__ float red[8];
  int wid = threadIdx.x >> 6, lane = threadIdx.x & 63;
  if (lane == 0) { red[wid] = s1; red[4 + wid] = s2; }
  __syncthreads();
  float t1 = red[0] + red[1] + red[2] + red[3];
  float t2 = red[4] + red[5] + red[6] + red[7];
  float mu = t1 * (1.0f / Cc);
  float var = t2 * (1.0f / Cc) - mu * mu;
  float rs = rsqrtf(var + 1e-5f);
  float4 gv = *(const float4*)(g + c4);
  float4 bv = *(const float4*)(b + c4);
  ushort4 o;
  o.x = f2bf((v.x - mu) * rs * gv.x + bv.x);
  o.y = f2bf((v.y - mu) * rs * gv.y + bv.y);
  o.z = f2bf((v.z - mu) * rs * gv.z + bv.z);
  o.w = f2bf((v.w - mu) * rs * gv.w + bv.w);
  *(ushort4*)(out + (size_t)row * Cc + c4) = o;
}

__global__ __launch_bounds__(256) void ln_kernel(const float* __restrict__ x,
                                                 const float* __restrict__ g,
                                                 const float* __restrict__ b,
                                                 ushort* __restrict__ out) {
  ln_body(x, g, b, out, blockIdx.x);
}

// ---------------- Transpose-cast fp32 [R][C] -> bf16 [C][R] ----------------
__device__ __forceinline__ void tcast_body(const float* __restrict__ src,
                                           ushort* __restrict__ dst, int ldS,
                                           int ldD, int r0, int c0) {
  __shared__ float t[32][33];
  int c = threadIdx.x & 31, r8 = threadIdx.x >> 5;
#pragma unroll
  for (int i = 0; i < 4; ++i) {
    int r = r8 + i * 8;
    t[r][c] = src[(size_t)(r0 + r) * ldS + c0 + c];
  }
  __syncthreads();
#pragma unroll
  for (int i = 0; i < 4; ++i) {
    int rr = r8 + i * 8;
    dst[(size_t)(c0 + rr) * ldD + r0 + c] = f2bf(t[c][rr]);
  }
}

// Fused prep: qkv tcast (3072) | wp (1024) | w1 (4096) | w2 (4096) |
// bias-concat (12) | LN1 rows (8192). Branch is block-uniform.
__global__ __launch_bounds__(256) void prep_kernel(
    const float* __restrict__ wq, const float* __restrict__ wk,
    const float* __restrict__ wv, const float* __restrict__ wp,
    const float* __restrict__ w1, const float* __restrict__ w2,
    const float* __restrict__ bq, const float* __restrict__ bk,
    const float* __restrict__ bv, ushort* __restrict__ wqkvT,
    ushort* __restrict__ wpT, ushort* __restrict__ w1T,
    ushort* __restrict__ w2T, float* __restrict__ bqkv,
    const float* __restrict__ x, const float* __restrict__ g1,
    const float* __restrict__ be1, ushort* __restrict__ h1b) {
  int id = blockIdx.x;
  if (id < 3072) {
    int z = id >> 6, rem = id & 63;
    int zz = z >> 4, h = z & 15;
    const float* src =
        (zz == 0 ? wq : (zz == 1 ? wk : wv)) + (size_t)h * Cc * HSz;
    ushort* d = wqkvT + (size_t)(zz * 1024 + h * 64) * 1024;
    tcast_body(src, d, HSz, Cc, (rem & 31) * 32, (rem >> 5) * 32);
  } else if (id < 4096) {
    int rem = id - 3072;  // 32x32
    tcast_body(wp, wpT, 1024, 1024, (rem & 31) * 32, (rem >> 5) * 32);
  } else if (id < 8192) {
    int rem = id - 4096;  // (32,128)
    tcast_body(w1, w1T, 4096, 1024, (rem & 31) * 32, (rem >> 5) * 32);
  } else if (id < 12288) {
    int rem = id - 8192;  // (128,32)
    tcast_body(w2, w2T, 1024, 4096, (rem & 127) * 32, (rem >> 7) * 32);
  } else if (id < 12300) {
    int i = (id - 12288) * 256 + threadIdx.x;
    bqkv[i] = i < 1024 ? bq[i] : (i < 2048 ? bk[i - 1024] : bv[i - 2048]);
  } else {
    ln_body(x, g1, be1, h1b, id - 12300);  // LN1 fused
  }
}

// XCD-chunked bijective block swizzle (all grids %8 == 0).
__device__ __forceinline__ void xcd_swz(int& bx, int& by) {
  int bid = blockIdx.x + blockIdx.y * gridDim.x;
  int cpx = (gridDim.x * gridDim.y) >> 3;
  int id = (bid & 7) * cpx + (bid >> 3);
  bx = id % gridDim.x;
  by = id / gridDim.x;
}

// ============ 256x256 tile, BK=64, 8 waves (2Mx4N), 4-phase K-loop =========
template <int MH, int NH>
__device__ __forceinline__ void mfma16(f32x4 (&acc)[8][4], bf16x8 (&a)[4][2],
                                       bf16x8 (&b)[2][2]) {
#pragma unroll
  for (int m = 0; m < 4; ++m)
#pragma unroll
    for (int n = 0; n < 2; ++n)
#pragma unroll
      for (int kk = 0; kk < 2; ++kk)
        acc[MH * 4 + m][NH * 2 + n] = __builtin_amdgcn_mfma_f32_16x16x32_bf16(
            a[m][kk], b[n][kk], acc[MH * 4 + m][NH * 2 + n], 0, 0, 0);
}

__device__ __forceinline__ void gemm256_main(const ushort* __restrict__ A,
                                             const ushort* __restrict__ Bt,
                                             int m0, int n0,
                                             ushort* __restrict__ As,
                                             ushort* __restrict__ Bs,
                                             f32x4 (&acc)[8][4]) {
  constexpr int NKT = 16;  // K = 1024
  int tid = threadIdx.x, wid = tid >> 6, lane = tid & 63;
  int wr = wid >> 2, wc = wid & 3, fr = lane & 15, fq = lane >> 4;
  const ushort* Ag = A + (size_t)m0 * 1024;
  const ushort* Bg = Bt + (size_t)n0 * 1024;
  int r0 = tid >> 3, r1 = 64 + (tid >> 3);
  int sc = ((tid & 7) ^ ((tid >> 3) & 7)) << 3;

  auto stage = [&](int ktn, int h, int ns) {  // h: 0=A-h0 1=A-h1 2=B-h0 3=B-h1
    const ushort* g = (h < 2) ? Ag : Bg;
    ushort* l = ((h < 2) ? As : Bs) + ns * 16384 + (h & 1) * 8192;
    int kcol = ktn * 64, rbase = (h & 1) * 128;
    gload16(g + (size_t)(rbase + r0) * 1024 + kcol + sc, l + (size_t)wid * 512);
    gload16(g + (size_t)(rbase + r1) * 1024 + kcol + sc,
            l + (size_t)(512 + wid * 64) * 8);
  };
  auto readA = [&](int slot, int mh, bf16x8 (&a)[4][2]) {
#pragma unroll
    for (int m = 0; m < 4; ++m) {
      int row = wr * 128 + mh * 64 + m * 16 + fr;
#pragma unroll
      for (int kk = 0; kk < 2; ++kk)
        a[m][kk] = *(const bf16x8*)&As[slot * 16384 + row * 64 +
                                       (((kk * 4 + fq) ^ (row & 7)) << 3)];
    }
  };
  auto readB = [&](int slot, int nh, bf16x8 (&b)[2][2]) {
#pragma unroll
    for (int n = 0; n < 2; ++n) {
      int row = wc * 64 + nh * 32 + n * 16 + fr;
#pragma unroll
      for (int kk = 0; kk < 2; ++kk)
        b[n][kk] = *(const bf16x8*)&Bs[slot * 16384 + row * 64 +
                                       (((kk * 4 + fq) ^ (row & 7)) << 3)];
    }
  };

  stage(0, 0, 0); stage(0, 1, 0); stage(0, 2, 0); stage(0, 3, 0);
  VMCNT(0);
  BARRIER;

  bf16x8 a[4][2], b0[2][2], b1[2][2];
#pragma unroll 1
  for (int kt = 0; kt < NKT; ++kt) {
    int slot = kt & 1, ns = slot ^ 1;
    bool st = (kt + 1 < NKT);
    readA(slot, 0, a);
    readB(slot, 0, b0);
    if (st) { stage(kt + 1, 0, ns); stage(kt + 1, 2, ns); }
    BARRIER;
    LGKM0;
    __builtin_amdgcn_s_setprio(1);
    mfma16<0, 0>(acc, a, b0);
    __builtin_amdgcn_s_setprio(0);
    BARRIER;
    readB(slot, 1, b1);
    if (st) { stage(kt + 1, 1, ns); stage(kt + 1, 3, ns); }
    BARRIER;
    LGKM0;
    __builtin_amdgcn_s_setprio(1);
    mfma16<0, 1>(acc, a, b1);
    __builtin_amdgcn_s_setprio(0);
    BARRIER;
    readA(slot, 1, a);
    BARRIER;
    LGKM0;
    __builtin_amdgcn_s_setprio(1);
    mfma16<1, 0>(acc, a, b0);
    __builtin_amdgcn_s_setprio(0);
    BARRIER;
    __builtin_amdgcn_s_setprio(1);
    mfma16<1, 1>(acc, a, b1);
    __builtin_amdgcn_s_setprio(0);
    VMCNT(0);
    BARRIER;
  }
}

// FFN1: ffh = relu(h1b @ w1T^T + b1), bf16 out [8192][4096]
__global__ __launch_bounds__(512, 2) void gemm256_relu(
    const ushort* __restrict__ A, const ushort* __restrict__ Bt,
    const float* __restrict__ bias, ushort* __restrict__ Cout, int ldc) {
  __shared__ __align__(16) ushort As[2 * 256 * 64];
  __shared__ __align__(16) ushort Bs[2 * 256 * 64];
  f32x4 acc[8][4] = {};
  int bx, by;
  xcd_swz(bx, by);
  int m0 = by * 256, n0 = bx * 256;
  gemm256_main(A, Bt, m0, n0, As, Bs, acc);
  int lane = threadIdx.x & 63, wid = threadIdx.x >> 6;
  int wr = wid >> 2, wc = wid & 3, fr = lane & 15, fq = lane >> 4;
#pragma unroll
  for (int i = 0; i < 8; ++i) {
    int gm = m0 + wr * 128 + (i >> 2) * 64 + (i & 3) * 16 + fq * 4;
#pragma unroll
    for (int j2 = 0; j2 < 4; ++j2) {
      int gn = n0 + wc * 64 + (j2 >> 1) * 32 + (j2 & 1) * 16 + fr;
      float bsv = bias[gn];
#pragma unroll
      for (int j = 0; j < 4; ++j)
        Cout[(size_t)(gm + j) * ldc + gn] = f2bf(fmaxf(acc[i][j2][j] + bsv, 0.f));
    }
  }
}

// ===== QKV: 256Mx192N tile, BK=64, 8 waves (2Mx4N), 3-phase K-loop ========
__global__ __launch_bounds__(512, 2) void gemm192_qkv(
    const ushort* __restrict__ A, const ushort* __restrict__ Bt,
    const float* __restrict__ bias, ushort* __restrict__ q,
    ushort* __restrict__ k, ushort* __restrict__ vt) {
  __shared__ __align__(16) ushort As[2 * 256 * 64];
  __shared__ __align__(16) ushort Bs[2 * 192 * 64];
  f32x4 acc[8][3] = {};
  int bx, by;
  xcd_swz(bx, by);
  int m0 = by * 256, n0 = bx * 192;
  int tid = threadIdx.x, wid = tid >> 6, lane = tid & 63;
  int wr = wid >> 2, wc = wid & 3, fr = lane & 15, fq = lane >> 4;
  const ushort* Ag = A + (size_t)m0 * 1024;
  const ushort* Bg = Bt + (size_t)n0 * 1024;
  int r0 = tid >> 3;
  int sc = ((tid & 7) ^ ((tid >> 3) & 7)) << 3;
  constexpr int NKT = 16;  // K = 1024

  auto stageA = [&](int ktn, int c, int ns) {
    ushort* l = As + ns * 16384 + c * 4096;
    gload16(Ag + (size_t)(c * 64 + r0) * 1024 + ktn * 64 + sc,
            l + (size_t)wid * 512);
  };
  auto stageB = [&](int ktn, int c, int ns) {
    ushort* l = Bs + ns * 12288 + c * 4096;
    gload16(Bg + (size_t)(c * 64 + r0) * 1024 + ktn * 64 + sc,
            l + (size_t)wid * 512);
  };
  auto readA = [&](int slot, int mh, bf16x8 (&a)[4][2]) {
#pragma unroll
    for (int m = 0; m < 4; ++m) {
      int row = wr * 128 + mh * 64 + m * 16 + fr;
#pragma unroll
      for (int kk = 0; kk < 2; ++kk)
        a[m][kk] = *(const bf16x8*)&As[slot * 16384 + row * 64 +
                                       (((kk * 4 + fq) ^ (row & 7)) << 3)];
    }
  };
  auto readB = [&](int slot, int nh, bf16x8 (&b)[2]) {
    int row = wc * 48 + nh * 16 + fr;
#pragma unroll
    for (int kk = 0; kk < 2; ++kk)
      b[kk] = *(const bf16x8*)&Bs[slot * 12288 + row * 64 +
                                  (((kk * 4 + fq) ^ (row & 7)) << 3)];
  };
  auto mfma16n = [&](int nh, bf16x8 (&a0)[4][2], bf16x8 (&a1)[4][2],
                     bf16x8 (&b)[2]) {
#pragma unroll
    for (int m = 0; m < 4; ++m)
#pragma unroll
      for (int kk = 0; kk < 2; ++kk)
        acc[m][nh] = __builtin_amdgcn_mfma_f32_16x16x32_bf16(
            a0[m][kk], b[kk], acc[m][nh], 0, 0, 0);
#pragma unroll
    for (int m = 0; m < 4; ++m)
#pragma unroll
      for (int kk = 0; kk < 2; ++kk)
        acc[4 + m][nh] = __builtin_amdgcn_mfma_f32_16x16x32_bf16(
            a1[m][kk], b[kk], acc[4 + m][nh], 0, 0, 0);
  };

  stageA(0, 0, 0); stageA(0, 1, 0); stageA(0, 2, 0); stageA(0, 3, 0);
  stageB(0, 0, 0); stageB(0, 1, 0); stageB(0, 2, 0);
  VMCNT(0);
  BARRIER;

  bf16x8 a0[4][2], a1[4][2], b0[2], b1[2], b2[2];
#pragma unroll 1
  for (int kt = 0; kt < NKT; ++kt) {
    int slot = kt & 1, ns = slot ^ 1;
    bool st = (kt + 1 < NKT);
    readA(slot, 0, a0);
    readA(slot, 1, a1);
    readB(slot, 0, b0);
    if (st) { stageA(kt + 1, 0, ns); stageA(kt + 1, 1, ns); stageB(kt + 1, 0, ns); }
    BARRIER;
    LGKM0;
    __builtin_amdgcn_s_setprio(1);
    mfma16n(0, a0, a1, b0);
    __builtin_amdgcn_s_setprio(0);
    BARRIER;
    readB(slot, 1, b1);
    if (st) { stageA(kt + 1, 2, ns); stageA(kt + 1, 3, ns); stageB(kt + 1, 1, ns); }
    BARRIER;
    LGKM0;
    __builtin_amdgcn_s_setprio(1);
    mfma16n(1, a0, a1, b1);
    __builtin_amdgcn_s_setprio(0);
    BARRIER;
    readB(slot, 2, b2);
    if (st) { stageB(kt + 1, 2, ns); }
    BARRIER;
    LGKM0;
    __builtin_amdgcn_s_setprio(1);
    mfma16n(2, a0, a1, b2);
    __builtin_amdgcn_s_setprio(0);
    VMCNT(0);
    BARRIER;
  }

  const float qscale = 1.4426950408889634f / 32.0f;  // log2e * C^-0.5
#pragma unroll
  for (int i = 0; i < 8; ++i) {
    int gm = m0 + wr * 128 + (i >> 2) * 64 + (i & 3) * 16 + fq * 4;
#pragma unroll
    for (int nh = 0; nh < 3; ++nh) {
      int gn = n0 + wc * 48 + nh * 16 + fr;
      float bsv = bias[gn];
      if (gn < 1024) {
#pragma unroll
        for (int j = 0; j < 4; ++j)
          q[(size_t)(gm + j) * 1024 + gn] = f2bf((acc[i][nh][j] + bsv) * qscale);
      } else if (gn < 2048) {
        int col = gn - 1024;
#pragma unroll
        for (int j = 0; j < 4; ++j)
          k[(size_t)(gm + j) * 1024 + col] = f2bf(acc[i][nh][j] + bsv);
      } else {
        int dd = gn - 2048, h = dd >> 6, d = dd & 63;
        int bbr = gm >> 11, t = gm & 2047;
        ushort4 pw = {f2bf(acc[i][nh][0] + bsv), f2bf(acc[i][nh][1] + bsv),
                      f2bf(acc[i][nh][2] + bsv), f2bf(acc[i][nh][3] + bsv)};
        *(ushort4*)&vt[(((size_t)(bbr * 16 + h)) * 64 + d) * 2048 + t] = pw;
      }
    }
  }
}

// -------- 128x128 bf16 GEMM, 2-slot ring + issue-after-barrier prefetch ---
__device__ __forceinline__ void gemm_main(const ushort* __restrict__ A, int lda,
                                          const ushort* __restrict__ Bt, int ldb,
                                          int K, int m0, int n0,
                                          ushort* __restrict__ As,
                                          ushort* __restrict__ Bs,
                                          f32x4 (&acc)[4][2]) {
  int tid = threadIdx.x, wid = tid >> 6, lane = tid & 63;
  int wr = wid >> 2, wc = wid & 3, fr = lane & 15, fq = lane >> 4;
  const ushort* Ag = A + (size_t)m0 * lda;
  const ushort* Bg = Bt + (size_t)n0 * ldb;
  int NKT = K >> 6;
  auto stage = [&](int ktn, int sl) {
#pragma unroll
    for (int c = 0; c < 2; ++c) {
      int slot = c * 512 + tid;
      int row = slot >> 3, s = slot & 7;
      int sw = (s << 3) ^ ((row & 7) << 3);
      gload16(Ag + (size_t)row * lda + ktn * 64 + sw,
              As + sl * 8192 + (size_t)(c * 512 + wid * 64) * 8);
      gload16(Bg + (size_t)row * ldb + ktn * 64 + sw,
              Bs + sl * 8192 + (size_t)(c * 512 + wid * 64) * 8);
    }
  };

  stage(0, 0);  // prologue
#pragma unroll 1
  for (int kt = 0; kt < NKT; ++kt) {
    int c = kt & 1;
    __syncthreads();  // tile kt landed; WAR-safe for slot c^1
    if (kt + 1 < NKT) stage(kt + 1, c ^ 1);
    bf16x8 av[4][2], bv[2][2];
#pragma unroll
    for (int m = 0; m < 4; ++m) {
      int row = wr * 64 + m * 16 + fr;
#pragma unroll
      for (int ks = 0; ks < 2; ++ks)
        av[m][ks] = *(const bf16x8*)&As[c * 8192 + row * 64 +
                                        (((ks * 4 + fq) ^ (row & 7)) << 3)];
    }
#pragma unroll
    for (int n = 0; n < 2; ++n) {
      int row = wc * 32 + n * 16 + fr;
#pragma unroll
      for (int ks = 0; ks < 2; ++ks)
        bv[n][ks] = *(const bf16x8*)&Bs[c * 8192 + row * 64 +
                                        (((ks * 4 + fq) ^ (row & 7)) << 3)];
    }
    __builtin_amdgcn_s_setprio(1);
#pragma unroll
    for (int m = 0; m < 4; ++m)
#pragma unroll
      for (int n = 0; n < 2; ++n)
#pragma unroll
        for (int ks = 0; ks < 2; ++ks)
          acc[m][n] = __builtin_amdgcn_mfma_f32_16x16x32_bf16(
              av[m][ks], bv[n][ks], acc[m][n], 0, 0, 0);
    __builtin_amdgcn_s_setprio(0);
  }
}

template <bool RELU, bool HASRES, bool OUTBF16>
__global__ __launch_bounds__(512) void gemm_bf16(
    const ushort* __restrict__ A, int lda, const ushort* __restrict__ Bt,
    int ldb, const float* __restrict__ bias, const float* __restrict__ res,
    void* __restrict__ Cout, int ldc, int K) {
  __shared__ __align__(16) ushort As[2 * 128 * 64];
  __shared__ __align__(16) ushort Bs[2 * 128 * 64];
  f32x4 acc[4][2] = {};
  int bx, by;
  xcd_swz(bx, by);
  int m0 = by * 128, n0 = bx * 128;
  gemm_main(A, lda, Bt, ldb, K, m0, n0, As, Bs, acc);
  int lane = threadIdx.x & 63, wid = threadIdx.x >> 6;
  int wr = wid >> 2, wc = wid & 3, fr = lane & 15, fq = lane >> 4;
#pragma unroll
  for (int m = 0; m < 4; ++m) {
    int gm = m0 + wr * 64 + m * 16 + fq * 4;
#pragma unroll
    for (int n = 0; n < 2; ++n) {
      int gn = n0 + wc * 32 + n * 16 + fr;
      float bsv = bias[gn];
#pragma unroll
      for (int j = 0; j < 4; ++j) {
        int row = gm + j;
        float v = acc[m][n][j] + bsv;
        if constexpr (HASRES) v += res[(size_t)row * ldc + gn];
        if constexpr (RELU) v = fmaxf(v, 0.f);
        if constexpr (OUTBF16)
          ((ushort*)Cout)[(size_t)row * ldc + gn] = f2bf(v);
        else
          ((float*)Cout)[(size_t)row * ldc + gn] = v;
      }
    }
  }
}

// ------- MFMA flash attention (pass-merged pair, shared K/V staging) -------
// grid (8, 64): block handles q-tiles A=i and B=15-i in ONE kt loop over
// B's KV range; A participates while in range. K/V staged once per kt
// (shared), barriers = ntB instead of ntA+ntB. l via ones-column MFMA.
constexpr int QB = 128, KVB = 64;
__global__ __launch_bounds__(512, 4) void attn_kernel(
    const ushort* __restrict__ Qb, const ushort* __restrict__ Kb,
    const ushort* __restrict__ Vt, ushort* __restrict__ att) {
  __shared__ __align__(16) ushort Klds[2][64 * 64];
  __shared__ __align__(16) ushort Vlds[2][64 * 64];
  __shared__ __align__(16) ushort Plds[8][16 * 64];
  int tid = threadIdx.x, wid = tid >> 6, lane = tid & 63;
  int fr = lane & 15, fq = lane >> 4;
  int bh = blockIdx.y, bb = bh >> 4, hh = bh & 15;
  const ushort* qkbase = Qb + ((size_t)bb * Tt) * Cc + hh * HSz;
  const ushort* Kbase = Kb + ((size_t)bb * Tt) * Cc + hh * HSz;
  const ushort* Vbase = Vt + ((size_t)(bb * Hh + hh)) * HSz * Tt;
  int srow = tid >> 3;
  int ssw = ((tid & 7) << 3) ^ ((srow & 7) << 3);
  bf16x8 vones;
#pragma unroll
  for (int i = 0; i < 8; ++i) vones[i] = (short)0x3F80;  // bf16 1.0

  int qtA = blockIdx.x, qtB = (Tt / QB - 1) - blockIdx.x;  // A small, B big
  int q0wA = qtA * QB + wid * 16, q0wB = qtB * QB + wid * 16;
  int NT = qtB * 2 + 2;  // B's tile count (>= A's)

  bf16x8 QregA[2], QregB[2];
#pragma unroll
  for (int d2 = 0; d2 < 2; ++d2) {
    QregA[d2] = *(const bf16x8*)(qkbase + (size_t)(q0wA + fr) * Cc + d2 * 32 + fq * 8);
    QregB[d2] = *(const bf16x8*)(qkbase + (size_t)(q0wB + fr) * Cc + d2 * 32 + fq * 8);
  }
  f32x4 OaA[4] = {}, OaB[4] = {};
  f32x4 OlA = {}, OlB = {};
  float mrowA = -1e30f, mrowB = -1e30f;

  char* pbase = (char*)Plds[wid] + fr * 128;

  // per-tile compute body (QK^T -> softmax -> P -> PV -> l), round-16 logic
  auto process = [&](int q0w, bf16x8 (&Qreg)[2], f32x4 (&Oa)[4], f32x4& Ol,
                     float& mrow, int t0, const char* Kc, const char* Vc) {
    bf16x8 kf[4][2];
#pragma unroll
    for (int ks = 0; ks < 4; ++ks)
#pragma unroll
      for (int d2 = 0; d2 < 2; ++d2) {
        int row = ks * 16 + fr;
        int off = (d2 * 64 + fq * 16) ^ ((row & 7) << 4);
        kf[ks][d2] = *(const bf16x8*)(Kc + row * 128 + off);
      }
    f32x4 accs[4] = {};
    __builtin_amdgcn_s_setprio(1);
#pragma unroll
    for (int ks = 0; ks < 4; ++ks) {
      accs[ks] = __builtin_amdgcn_mfma_f32_16x16x32_bf16(
          kf[ks][0], Qreg[0], accs[ks], 0, 0, 0);
      accs[ks] = __builtin_amdgcn_mfma_f32_16x16x32_bf16(
          kf[ks][1], Qreg[1], accs[ks], 0, 0, 0);
    }
    __builtin_amdgcn_s_setprio(0);

    float sv[4][4];
    if (t0 + 63 <= q0w) {
#pragma unroll
      for (int ks = 0; ks < 4; ++ks)
#pragma unroll
        for (int j = 0; j < 4; ++j) sv[ks][j] = accs[ks][j];
    } else {
      int qg = q0w + fr;
#pragma unroll
      for (int ks = 0; ks < 4; ++ks)
#pragma unroll
        for (int j = 0; j < 4; ++j) {
          int kg = t0 + ks * 16 + fq * 4 + j;
          sv[ks][j] = (kg <= qg) ? accs[ks][j] : -1e30f;
        }
    }
    float m0a = fmaxf(fmaxf(sv[0][0], sv[0][1]), fmaxf(sv[0][2], sv[0][3]));
    float m1a = fmaxf(fmaxf(sv[1][0], sv[1][1]), fmaxf(sv[1][2], sv[1][3]));
    float m2a = fmaxf(fmaxf(sv[2][0], sv[2][1]), fmaxf(sv[2][2], sv[2][3]));
    float m3a = fmaxf(fmaxf(sv[3][0], sv[3][1]), fmaxf(sv[3][2], sv[3][3]));
    float vmax = fmaxf(fmaxf(m0a, m1a), fmaxf(m2a, m3a));

    float mnew = mrow;
    if (!__all(vmax <= mrow + 11.0f)) {
      float rmax = fmaxf(vmax, __shfl_xor(vmax, 16));
      rmax = fmaxf(rmax, __shfl_xor(rmax, 32));
      mnew = fmaxf(mrow, rmax);
      float sf = exp2f(mrow - mnew);
      mrow = mnew;
#pragma unroll
      for (int j = 0; j < 4; ++j) {
        float sfo = __shfl(sf, fq * 4 + j);
        Ol[j] *= sfo;
#pragma unroll
        for (int ds = 0; ds < 4; ++ds) Oa[ds][j] *= sfo;
      }
    }
#pragma unroll
    for (int ks = 0; ks < 4; ++ks) {
      float p0 = exp2f(sv[ks][0] - mnew);
      float p1 = exp2f(sv[ks][1] - mnew);
      float p2 = exp2f(sv[ks][2] - mnew);
      float p3 = exp2f(sv[ks][3] - mnew);
      uint2 pw = {cvtpk_bf16(p0, p1), cvtpk_bf16(p2, p3)};
      int off = (ks * 32 + fq * 8) ^ ((fr & 7) << 4);
      *(uint2*)(pbase + off) = pw;
    }

    bf16x8 pf[2];
#pragma unroll
    for (int k2 = 0; k2 < 2; ++k2) {
      int off = (k2 * 64 + fq * 16) ^ ((fr & 7) << 4);
      pf[k2] = *(const bf16x8*)((const char*)Plds[wid] + fr * 128 + off);
    }
    __builtin_amdgcn_s_setprio(1);
#pragma unroll
    for (int ds = 0; ds < 4; ++ds) {
      bf16x8 vf0, vf1;
      int row = ds * 16 + fr;
      vf0 = *(const bf16x8*)(Vc + row * 128 + ((0 * 64 + fq * 16) ^ ((row & 7) << 4)));
      vf1 = *(const bf16x8*)(Vc + row * 128 + ((1 * 64 + fq * 16) ^ ((row & 7) << 4)));
      Oa[ds] = __builtin_amdgcn_mfma_f32_16x16x32_bf16(pf[0], vf0, Oa[ds], 0, 0, 0);
      Oa[ds] = __builtin_amdgcn_mfma_f32_16x16x32_bf16(pf[1], vf1, Oa[ds], 0, 0, 0);
    }
    Ol = __builtin_amdgcn_mfma_f32_16x16x32_bf16(pf[0], vones, Ol, 0, 0, 0);
    Ol = __builtin_amdgcn_mfma_f32_16x16x32_bf16(pf[1], vones, Ol, 0, 0, 0);
    __builtin_amdgcn_s_setprio(0);
  };

  // prologue: stage tile 0 -> buf 0 (shared by both q-tiles)
  gload16(Kbase + (size_t)srow * Cc + ssw, (char*)Klds[0] + wid * 1024);
  gload16(Vbase + (size_t)srow * Tt + ssw, (char*)Vlds[0] + wid * 1024);

#pragma unroll 1
  for (int kt = 0; kt < NT; ++kt) {
    int t0 = kt * KVB;
    int c = kt & 1;
    __syncthreads();  // tile kt landed (implicit vmcnt(0)); WAR for buf c^1
    if (kt + 1 < NT) {
      int t0n = t0 + KVB;
      gload16(Kbase + (size_t)(t0n + srow) * Cc + ssw,
              (char*)Klds[c ^ 1] + wid * 1024);
      gload16(Vbase + (size_t)srow * Tt + t0n + ssw,
              (char*)Vlds[c ^ 1] + wid * 1024);
    }
    const char* Kc = (const char*)Klds[c];
    const char* Vc = (const char*)Vlds[c];
    // tile B always in range (NT = ntB); per-wave diagonal guard
    if (!(q0wB + 15 < t0)) process(q0wB, QregB, OaB, OlB, mrowB, t0, Kc, Vc);
    // tile A participates while its KV range lasts
    if (!(q0wA + 15 < t0)) process(q0wA, QregA, OaA, OlA, mrowA, t0, Kc, Vc);
  }

  // ---- epilogues: shuffle-free (Ol[j] = l for q = fq*4+j) ----
#pragma unroll
  for (int j = 0; j < 4; ++j) {
    float loA = 1.f / OlA[j];
    float loB = 1.f / OlB[j];
    int qgA = q0wA + fq * 4 + j;
    int qgB = q0wB + fq * 4 + j;
    ushort* orowA = att + (size_t)(bb * Tt + qgA) * Cc + hh * HSz;
    ushort* orowB = att + (size_t)(bb * Tt + qgB) * Cc + hh * HSz;
#pragma unroll
    for (int ds = 0; ds < 4; ++ds) {
      orowA[ds * 16 + fr] = f2bf(OaA[ds][j] * loA);
      orowB[ds * 16 + fr] = f2bf(OaB[ds][j] * loB);
    }
  }
}

extern "C" void kernel_launch(void* const* d_in, const int* in_sizes, int n_in,
                              void* d_out, int out_size, void* d_ws,
                              size_t ws_size, hipStream_t stream) {
  const float* x = (const float*)d_in[0];
  const float* wq = (const float*)d_in[1];
  const float* bq = (const float*)d_in[2];
  const float* wk = (const float*)d_in[3];
  const float* bk = (const float*)d_in[4];
  const float* wv = (const float*)d_in[5];
  const float* bv = (const float*)d_in[6];
  const float* wp = (const float*)d_in[7];
  const float* bp = (const float*)d_in[8];
  const float* w1 = (const float*)d_in[9];
  const float* b1 = (const float*)d_in[10];
  const float* w2 = (const float*)d_in[11];
  const float* b2 = (const float*)d_in[12];
  const float* g1 = (const float*)d_in[13];
  const float* be1 = (const float*)d_in[14];
  const float* g2 = (const float*)d_in[15];
  const float* be2 = (const float*)d_in[16];
  float* out = (float*)d_out;

  ushort* Qb = (ushort*)d_ws;                 // [8192][1024]
  ushort* Kb = Qb + (size_t)8388608;          // [8192][1024]
  ushort* Vt = Kb + (size_t)8388608;          // [4][16][64][2048]
  ushort* att = Vt + (size_t)8388608;         // [8192][1024]
  ushort* ffh = Qb;                           // [8192][4096] overlay
  ushort* h1b = att + (size_t)8388608;        // LN1/LN2 out
  float* x2 = (float*)(h1b + (size_t)8388608);
  ushort* wqkvT = (ushort*)(x2 + (size_t)8388608);  // [3072][1024]
  ushort* wpT = wqkvT + (size_t)3145728;            // [1024][1024]
  ushort* w1T = wpT + (size_t)1048576;              // [4096][1024]
  ushort* w2T = w1T + (size_t)4194304;              // [1024][4096]
  float* bqkv = (float*)(w2T + (size_t)4194304);    // [3072]

  // 0) weight prep + LN1 in one kernel (12300 + 8192 blocks)
  prep_kernel<<<dim3(20492), 256, 0, stream>>>(wq, wk, wv, wp, w1, w2, bq, bk,
                                               bv, wqkvT, wpT, w1T, w2T, bqkv,
                                               x, g1, be1, h1b);
  // 2) Q,K,Vt = h1b @ WqkvT^T + bqkv  (256x192 3-phase — grid 16x32)
  gemm192_qkv<<<dim3(16, 32), 512, 0, stream>>>(h1b, wqkvT, bqkv, Qb, Kb, Vt);
  // 3) att = causal_softmax(Q K^T) V  (pass-merged pair-balanced grid)
  attn_kernel<<<dim3(Tt / QB / 2, Bb * Hh), 512, 0, stream>>>(Qb, Kb, Vt, att);
  // 4) x2 = x + att @ wp + bp  (128^2 ring)
  gemm_bf16<false, true, false><<<dim3(8, 64), 512, 0, stream>>>(
      att, 1024, wpT, 1024, bp, x, x2, 1024, 1024);
  // 5) h2b = LN(x2)
  ln_kernel<<<dim3(Mrows), 256, 0, stream>>>(x2, g2, be2, h1b);
  // 6) ffh = relu(h2b @ w1 + b1)  (256^2 4-phase — grid 16x32)
  gemm256_relu<<<dim3(16, 32), 512, 0, stream>>>(h1b, w1T, b1, ffh, 4096);
  // 7) out = x2 + ffh @ w2 + b2  (128^2 ring)
  gemm_bf16<false, true, false><<<dim3(8, 64), 512, 0, stream>>>(
      ffh, 4096, w2T, 4096, b2, x2, out, 1024, 4096);
}

// Round 19
// 334.242 us; speedup vs baseline: 1.0195x; 1.0195x over previous
//
#include <hip/hip_runtime.h>

// Transformer block. Round 18: attn REVERTED to round-17 best (pass-merge
// was neutral/negative: not HBM- or barrier-bound) + head-locality XCD
// swizzle (all 8 q-tile blocks of a head co-located on one XCD -> K/V
// L2-resident, prefetch latency 900->~200cy). Everything else frozen.
//
// Workspace (~136 MiB): [Q|K|Vt|att] <- ffh overlay; [h1b][x2][weights][bqkv]

constexpr int Bb = 4, Tt = 2048, Cc = 1024, Hh = 16, HSz = 64, Ff = 4096;
constexpr int Mrows = Bb * Tt;  // 8192

typedef __attribute__((ext_vector_type(8))) short bf16x8;
typedef __attribute__((ext_vector_type(4))) float f32x4;

__device__ __forceinline__ ushort f2bf(float f) {
  uint u = __builtin_bit_cast(uint, f);
  uint r = (u + 0x7fffu + ((u >> 16) & 1u)) >> 16;
  return (ushort)r;
}
__device__ __forceinline__ float bf2f(ushort s) {
  return __builtin_bit_cast(float, ((uint)s) << 16);
}
__device__ __forceinline__ uint cvtpk_bf16(float lo, float hi) {
  uint r;
  asm("v_cvt_pk_bf16_f32 %0, %1, %2" : "=v"(r) : "v"(lo), "v"(hi));
  return r;
}
__device__ __forceinline__ void gload16(const void* g, void* l) {
  __builtin_amdgcn_global_load_lds(
      (const __attribute__((address_space(1))) void*)g,
      (__attribute__((address_space(3))) void*)l, 16, 0, 0);
}
#define VMCNT(n) asm volatile("s_waitcnt vmcnt(" #n ")" ::: "memory")
#define LGKM0                                          \
  do {                                                 \
    asm volatile("s_waitcnt lgkmcnt(0)" ::: "memory"); \
    __builtin_amdgcn_sched_barrier(0);                 \
  } while (0)
#define BARRIER __builtin_amdgcn_s_barrier()

// ---------------- LayerNorm body: fp32 in, bf16 out ----------------
__device__ __forceinline__ void ln_body(const float* __restrict__ x,
                                        const float* __restrict__ g,
                                        const float* __restrict__ b,
                                        ushort* __restrict__ out, int row) {
  const float* xr = x + (size_t)row * Cc;
  int c4 = threadIdx.x * 4;
  float4 v = *(const float4*)(xr + c4);
  float s1 = v.x + v.y + v.z + v.w;
  float s2 = v.x * v.x + v.y * v.y + v.z * v.z + v.w * v.w;
#pragma unroll
  for (int off = 32; off >= 1; off >>= 1) {
    s1 += __shfl_xor(s1, off);
    s2 += __shfl_xor(s2, off);
  }
  __shared__ float red[8];
  int wid = threadIdx.x >> 6, lane = threadIdx.x & 63;
  if (lane == 0) { red[wid] = s1; red[4 + wid] = s2; }
  __syncthreads();
  float t1 = red[0] + red[1] + red[2] + red[3];
  float t2 = red[4] + red[5] + red[6] + red[7];
  float mu = t1 * (1.0f / Cc);
  float var = t2 * (1.0f / Cc) - mu * mu;
  float rs = rsqrtf(var + 1e-5f);
  float4 gv = *(const float4*)(g + c4);
  float4 bv = *(const float4*)(b + c4);
  ushort4 o;
  o.x = f2bf((v.x - mu) * rs * gv.x + bv.x);
  o.y = f2bf((v.y - mu) * rs * gv.y + bv.y);
  o.z = f2bf((v.z - mu) * rs * gv.z + bv.z);
  o.w = f2bf((v.w - mu) * rs * gv.w + bv.w);
  *(ushort4*)(out + (size_t)row * Cc + c4) = o;
}

__global__ __launch_bounds__(256) void ln_kernel(const float* __restrict__ x,
                                                 const float* __restrict__ g,
                                                 const float* __restrict__ b,
                                                 ushort* __restrict__ out) {
  ln_body(x, g, b, out, blockIdx.x);
}

// ---------------- Transpose-cast fp32 [R][C] -> bf16 [C][R] ----------------
__device__ __forceinline__ void tcast_body(const float* __restrict__ src,
                                           ushort* __restrict__ dst, int ldS,
                                           int ldD, int r0, int c0) {
  __shared__ float t[32][33];
  int c = threadIdx.x & 31, r8 = threadIdx.x >> 5;
#pragma unroll
  for (int i = 0; i < 4; ++i) {
    int r = r8 + i * 8;
    t[r][c] = src[(size_t)(r0 + r) * ldS + c0 + c];
  }
  __syncthreads();
#pragma unroll
  for (int i = 0; i < 4; ++i) {
    int rr = r8 + i * 8;
    dst[(size_t)(c0 + rr) * ldD + r0 + c] = f2bf(t[c][rr]);
  }
}

// Fused prep: qkv tcast (3072) | wp (1024) | w1 (4096) | w2 (4096) |
// bias-concat (12) | LN1 rows (8192). Branch is block-uniform.
__global__ __launch_bounds__(256) void prep_kernel(
    const float* __restrict__ wq, const float* __restrict__ wk,
    const float* __restrict__ wv, const float* __restrict__ wp,
    const float* __restrict__ w1, const float* __restrict__ w2,
    const float* __restrict__ bq, const float* __restrict__ bk,
    const float* __restrict__ bv, ushort* __restrict__ wqkvT,
    ushort* __restrict__ wpT, ushort* __restrict__ w1T,
    ushort* __restrict__ w2T, float* __restrict__ bqkv,
    const float* __restrict__ x, const float* __restrict__ g1,
    const float* __restrict__ be1, ushort* __restrict__ h1b) {
  int id = blockIdx.x;
  if (id < 3072) {
    int z = id >> 6, rem = id & 63;
    int zz = z >> 4, h = z & 15;
    const float* src =
        (zz == 0 ? wq : (zz == 1 ? wk : wv)) + (size_t)h * Cc * HSz;
    ushort* d = wqkvT + (size_t)(zz * 1024 + h * 64) * 1024;
    tcast_body(src, d, HSz, Cc, (rem & 31) * 32, (rem >> 5) * 32);
  } else if (id < 4096) {
    int rem = id - 3072;  // 32x32
    tcast_body(wp, wpT, 1024, 1024, (rem & 31) * 32, (rem >> 5) * 32);
  } else if (id < 8192) {
    int rem = id - 4096;  // (32,128)
    tcast_body(w1, w1T, 4096, 1024, (rem & 31) * 32, (rem >> 5) * 32);
  } else if (id < 12288) {
    int rem = id - 8192;  // (128,32)
    tcast_body(w2, w2T, 1024, 4096, (rem & 127) * 32, (rem >> 7) * 32);
  } else if (id < 12300) {
    int i = (id - 12288) * 256 + threadIdx.x;
    bqkv[i] = i < 1024 ? bq[i] : (i < 2048 ? bk[i - 1024] : bv[i - 2048]);
  } else {
    ln_body(x, g1, be1, h1b, id - 12300);  // LN1 fused
  }
}

// XCD-chunked bijective block swizzle (all grids %8 == 0).
__device__ __forceinline__ void xcd_swz(int& bx, int& by) {
  int bid = blockIdx.x + blockIdx.y * gridDim.x;
  int cpx = (gridDim.x * gridDim.y) >> 3;
  int id = (bid & 7) * cpx + (bid >> 3);
  bx = id % gridDim.x;
  by = id / gridDim.x;
}

// ============ 256x256 tile, BK=64, 8 waves (2Mx4N), 4-phase K-loop =========
template <int MH, int NH>
__device__ __forceinline__ void mfma16(f32x4 (&acc)[8][4], bf16x8 (&a)[4][2],
                                       bf16x8 (&b)[2][2]) {
#pragma unroll
  for (int m = 0; m < 4; ++m)
#pragma unroll
    for (int n = 0; n < 2; ++n)
#pragma unroll
      for (int kk = 0; kk < 2; ++kk)
        acc[MH * 4 + m][NH * 2 + n] = __builtin_amdgcn_mfma_f32_16x16x32_bf16(
            a[m][kk], b[n][kk], acc[MH * 4 + m][NH * 2 + n], 0, 0, 0);
}

__device__ __forceinline__ void gemm256_main(const ushort* __restrict__ A,
                                             const ushort* __restrict__ Bt,
                                             int m0, int n0,
                                             ushort* __restrict__ As,
                                             ushort* __restrict__ Bs,
                                             f32x4 (&acc)[8][4]) {
  constexpr int NKT = 16;  // K = 1024
  int tid = threadIdx.x, wid = tid >> 6, lane = tid & 63;
  int wr = wid >> 2, wc = wid & 3, fr = lane & 15, fq = lane >> 4;
  const ushort* Ag = A + (size_t)m0 * 1024;
  const ushort* Bg = Bt + (size_t)n0 * 1024;
  int r0 = tid >> 3, r1 = 64 + (tid >> 3);
  int sc = ((tid & 7) ^ ((tid >> 3) & 7)) << 3;

  auto stage = [&](int ktn, int h, int ns) {  // h: 0=A-h0 1=A-h1 2=B-h0 3=B-h1
    const ushort* g = (h < 2) ? Ag : Bg;
    ushort* l = ((h < 2) ? As : Bs) + ns * 16384 + (h & 1) * 8192;
    int kcol = ktn * 64, rbase = (h & 1) * 128;
    gload16(g + (size_t)(rbase + r0) * 1024 + kcol + sc, l + (size_t)wid * 512);
    gload16(g + (size_t)(rbase + r1) * 1024 + kcol + sc,
            l + (size_t)(512 + wid * 64) * 8);
  };
  auto readA = [&](int slot, int mh, bf16x8 (&a)[4][2]) {
#pragma unroll
    for (int m = 0; m < 4; ++m) {
      int row = wr * 128 + mh * 64 + m * 16 + fr;
#pragma unroll
      for (int kk = 0; kk < 2; ++kk)
        a[m][kk] = *(const bf16x8*)&As[slot * 16384 + row * 64 +
                                       (((kk * 4 + fq) ^ (row & 7)) << 3)];
    }
  };
  auto readB = [&](int slot, int nh, bf16x8 (&b)[2][2]) {
#pragma unroll
    for (int n = 0; n < 2; ++n) {
      int row = wc * 64 + nh * 32 + n * 16 + fr;
#pragma unroll
      for (int kk = 0; kk < 2; ++kk)
        b[n][kk] = *(const bf16x8*)&Bs[slot * 16384 + row * 64 +
                                       (((kk * 4 + fq) ^ (row & 7)) << 3)];
    }
  };

  stage(0, 0, 0); stage(0, 1, 0); stage(0, 2, 0); stage(0, 3, 0);
  VMCNT(0);
  BARRIER;

  bf16x8 a[4][2], b0[2][2], b1[2][2];
#pragma unroll 1
  for (int kt = 0; kt < NKT; ++kt) {
    int slot = kt & 1, ns = slot ^ 1;
    bool st = (kt + 1 < NKT);
    readA(slot, 0, a);
    readB(slot, 0, b0);
    if (st) { stage(kt + 1, 0, ns); stage(kt + 1, 2, ns); }
    BARRIER;
    LGKM0;
    __builtin_amdgcn_s_setprio(1);
    mfma16<0, 0>(acc, a, b0);
    __builtin_amdgcn_s_setprio(0);
    BARRIER;
    readB(slot, 1, b1);
    if (st) { stage(kt + 1, 1, ns); stage(kt + 1, 3, ns); }
    BARRIER;
    LGKM0;
    __builtin_amdgcn_s_setprio(1);
    mfma16<0, 1>(acc, a, b1);
    __builtin_amdgcn_s_setprio(0);
    BARRIER;
    readA(slot, 1, a);
    BARRIER;
    LGKM0;
    __builtin_amdgcn_s_setprio(1);
    mfma16<1, 0>(acc, a, b0);
    __builtin_amdgcn_s_setprio(0);
    BARRIER;
    __builtin_amdgcn_s_setprio(1);
    mfma16<1, 1>(acc, a, b1);
    __builtin_amdgcn_s_setprio(0);
    VMCNT(0);
    BARRIER;
  }
}

// FFN1: ffh = relu(h1b @ w1T^T + b1), bf16 out [8192][4096]
__global__ __launch_bounds__(512, 2) void gemm256_relu(
    const ushort* __restrict__ A, const ushort* __restrict__ Bt,
    const float* __restrict__ bias, ushort* __restrict__ Cout, int ldc) {
  __shared__ __align__(16) ushort As[2 * 256 * 64];
  __shared__ __align__(16) ushort Bs[2 * 256 * 64];
  f32x4 acc[8][4] = {};
  int bx, by;
  xcd_swz(bx, by);
  int m0 = by * 256, n0 = bx * 256;
  gemm256_main(A, Bt, m0, n0, As, Bs, acc);
  int lane = threadIdx.x & 63, wid = threadIdx.x >> 6;
  int wr = wid >> 2, wc = wid & 3, fr = lane & 15, fq = lane >> 4;
#pragma unroll
  for (int i = 0; i < 8; ++i) {
    int gm = m0 + wr * 128 + (i >> 2) * 64 + (i & 3) * 16 + fq * 4;
#pragma unroll
    for (int j2 = 0; j2 < 4; ++j2) {
      int gn = n0 + wc * 64 + (j2 >> 1) * 32 + (j2 & 1) * 16 + fr;
      float bsv = bias[gn];
#pragma unroll
      for (int j = 0; j < 4; ++j)
        Cout[(size_t)(gm + j) * ldc + gn] = f2bf(fmaxf(acc[i][j2][j] + bsv, 0.f));
    }
  }
}

// ===== QKV: 256Mx192N tile, BK=64, 8 waves (2Mx4N), 3-phase K-loop ========
__global__ __launch_bounds__(512, 2) void gemm192_qkv(
    const ushort* __restrict__ A, const ushort* __restrict__ Bt,
    const float* __restrict__ bias, ushort* __restrict__ q,
    ushort* __restrict__ k, ushort* __restrict__ vt) {
  __shared__ __align__(16) ushort As[2 * 256 * 64];
  __shared__ __align__(16) ushort Bs[2 * 192 * 64];
  f32x4 acc[8][3] = {};
  int bx, by;
  xcd_swz(bx, by);
  int m0 = by * 256, n0 = bx * 192;
  int tid = threadIdx.x, wid = tid >> 6, lane = tid & 63;
  int wr = wid >> 2, wc = wid & 3, fr = lane & 15, fq = lane >> 4;
  const ushort* Ag = A + (size_t)m0 * 1024;
  const ushort* Bg = Bt + (size_t)n0 * 1024;
  int r0 = tid >> 3;
  int sc = ((tid & 7) ^ ((tid >> 3) & 7)) << 3;
  constexpr int NKT = 16;  // K = 1024

  auto stageA = [&](int ktn, int c, int ns) {
    ushort* l = As + ns * 16384 + c * 4096;
    gload16(Ag + (size_t)(c * 64 + r0) * 1024 + ktn * 64 + sc,
            l + (size_t)wid * 512);
  };
  auto stageB = [&](int ktn, int c, int ns) {
    ushort* l = Bs + ns * 12288 + c * 4096;
    gload16(Bg + (size_t)(c * 64 + r0) * 1024 + ktn * 64 + sc,
            l + (size_t)wid * 512);
  };
  auto readA = [&](int slot, int mh, bf16x8 (&a)[4][2]) {
#pragma unroll
    for (int m = 0; m < 4; ++m) {
      int row = wr * 128 + mh * 64 + m * 16 + fr;
#pragma unroll
      for (int kk = 0; kk < 2; ++kk)
        a[m][kk] = *(const bf16x8*)&As[slot * 16384 + row * 64 +
                                       (((kk * 4 + fq) ^ (row & 7)) << 3)];
    }
  };
  auto readB = [&](int slot, int nh, bf16x8 (&b)[2]) {
    int row = wc * 48 + nh * 16 + fr;
#pragma unroll
    for (int kk = 0; kk < 2; ++kk)
      b[kk] = *(const bf16x8*)&Bs[slot * 12288 + row * 64 +
                                  (((kk * 4 + fq) ^ (row & 7)) << 3)];
  };
  auto mfma16n = [&](int nh, bf16x8 (&a0)[4][2], bf16x8 (&a1)[4][2],
                     bf16x8 (&b)[2]) {
#pragma unroll
    for (int m = 0; m < 4; ++m)
#pragma unroll
      for (int kk = 0; kk < 2; ++kk)
        acc[m][nh] = __builtin_amdgcn_mfma_f32_16x16x32_bf16(
            a0[m][kk], b[kk], acc[m][nh], 0, 0, 0);
#pragma unroll
    for (int m = 0; m < 4; ++m)
#pragma unroll
      for (int kk = 0; kk < 2; ++kk)
        acc[4 + m][nh] = __builtin_amdgcn_mfma_f32_16x16x32_bf16(
            a1[m][kk], b[kk], acc[4 + m][nh], 0, 0, 0);
  };

  stageA(0, 0, 0); stageA(0, 1, 0); stageA(0, 2, 0); stageA(0, 3, 0);
  stageB(0, 0, 0); stageB(0, 1, 0); stageB(0, 2, 0);
  VMCNT(0);
  BARRIER;

  bf16x8 a0[4][2], a1[4][2], b0[2], b1[2], b2[2];
#pragma unroll 1
  for (int kt = 0; kt < NKT; ++kt) {
    int slot = kt & 1, ns = slot ^ 1;
    bool st = (kt + 1 < NKT);
    readA(slot, 0, a0);
    readA(slot, 1, a1);
    readB(slot, 0, b0);
    if (st) { stageA(kt + 1, 0, ns); stageA(kt + 1, 1, ns); stageB(kt + 1, 0, ns); }
    BARRIER;
    LGKM0;
    __builtin_amdgcn_s_setprio(1);
    mfma16n(0, a0, a1, b0);
    __builtin_amdgcn_s_setprio(0);
    BARRIER;
    readB(slot, 1, b1);
    if (st) { stageA(kt + 1, 2, ns); stageA(kt + 1, 3, ns); stageB(kt + 1, 1, ns); }
    BARRIER;
    LGKM0;
    __builtin_amdgcn_s_setprio(1);
    mfma16n(1, a0, a1, b1);
    __builtin_amdgcn_s_setprio(0);
    BARRIER;
    readB(slot, 2, b2);
    if (st) { stageB(kt + 1, 2, ns); }
    BARRIER;
    LGKM0;
    __builtin_amdgcn_s_setprio(1);
    mfma16n(2, a0, a1, b2);
    __builtin_amdgcn_s_setprio(0);
    VMCNT(0);
    BARRIER;
  }

  const float qscale = 1.4426950408889634f / 32.0f;  // log2e * C^-0.5
#pragma unroll
  for (int i = 0; i < 8; ++i) {
    int gm = m0 + wr * 128 + (i >> 2) * 64 + (i & 3) * 16 + fq * 4;
#pragma unroll
    for (int nh = 0; nh < 3; ++nh) {
      int gn = n0 + wc * 48 + nh * 16 + fr;
      float bsv = bias[gn];
      if (gn < 1024) {
#pragma unroll
        for (int j = 0; j < 4; ++j)
          q[(size_t)(gm + j) * 1024 + gn] = f2bf((acc[i][nh][j] + bsv) * qscale);
      } else if (gn < 2048) {
        int col = gn - 1024;
#pragma unroll
        for (int j = 0; j < 4; ++j)
          k[(size_t)(gm + j) * 1024 + col] = f2bf(acc[i][nh][j] + bsv);
      } else {
        int dd = gn - 2048, h = dd >> 6, d = dd & 63;
        int bbr = gm >> 11, t = gm & 2047;
        ushort4 pw = {f2bf(acc[i][nh][0] + bsv), f2bf(acc[i][nh][1] + bsv),
                      f2bf(acc[i][nh][2] + bsv), f2bf(acc[i][nh][3] + bsv)};
        *(ushort4*)&vt[(((size_t)(bbr * 16 + h)) * 64 + d) * 2048 + t] = pw;
      }
    }
  }
}

// -------- 128x128 bf16 GEMM, 2-slot ring + issue-after-barrier prefetch ---
__device__ __forceinline__ void gemm_main(const ushort* __restrict__ A, int lda,
                                          const ushort* __restrict__ Bt, int ldb,
                                          int K, int m0, int n0,
                                          ushort* __restrict__ As,
                                          ushort* __restrict__ Bs,
                                          f32x4 (&acc)[4][2]) {
  int tid = threadIdx.x, wid = tid >> 6, lane = tid & 63;
  int wr = wid >> 2, wc = wid & 3, fr = lane & 15, fq = lane >> 4;
  const ushort* Ag = A + (size_t)m0 * lda;
  const ushort* Bg = Bt + (size_t)n0 * ldb;
  int NKT = K >> 6;
  auto stage = [&](int ktn, int sl) {
#pragma unroll
    for (int c = 0; c < 2; ++c) {
      int slot = c * 512 + tid;
      int row = slot >> 3, s = slot & 7;
      int sw = (s << 3) ^ ((row & 7) << 3);
      gload16(Ag + (size_t)row * lda + ktn * 64 + sw,
              As + sl * 8192 + (size_t)(c * 512 + wid * 64) * 8);
      gload16(Bg + (size_t)row * ldb + ktn * 64 + sw,
              Bs + sl * 8192 + (size_t)(c * 512 + wid * 64) * 8);
    }
  };

  stage(0, 0);  // prologue
#pragma unroll 1
  for (int kt = 0; kt < NKT; ++kt) {
    int c = kt & 1;
    __syncthreads();  // tile kt landed; WAR-safe for slot c^1
    if (kt + 1 < NKT) stage(kt + 1, c ^ 1);
    bf16x8 av[4][2], bv[2][2];
#pragma unroll
    for (int m = 0; m < 4; ++m) {
      int row = wr * 64 + m * 16 + fr;
#pragma unroll
      for (int ks = 0; ks < 2; ++ks)
        av[m][ks] = *(const bf16x8*)&As[c * 8192 + row * 64 +
                                        (((ks * 4 + fq) ^ (row & 7)) << 3)];
    }
#pragma unroll
    for (int n = 0; n < 2; ++n) {
      int row = wc * 32 + n * 16 + fr;
#pragma unroll
      for (int ks = 0; ks < 2; ++ks)
        bv[n][ks] = *(const bf16x8*)&Bs[c * 8192 + row * 64 +
                                        (((ks * 4 + fq) ^ (row & 7)) << 3)];
    }
    __builtin_amdgcn_s_setprio(1);
#pragma unroll
    for (int m = 0; m < 4; ++m)
#pragma unroll
      for (int n = 0; n < 2; ++n)
#pragma unroll
        for (int ks = 0; ks < 2; ++ks)
          acc[m][n] = __builtin_amdgcn_mfma_f32_16x16x32_bf16(
              av[m][ks], bv[n][ks], acc[m][n], 0, 0, 0);
    __builtin_amdgcn_s_setprio(0);
  }
}

template <bool RELU, bool HASRES, bool OUTBF16>
__global__ __launch_bounds__(512) void gemm_bf16(
    const ushort* __restrict__ A, int lda, const ushort* __restrict__ Bt,
    int ldb, const float* __restrict__ bias, const float* __restrict__ res,
    void* __restrict__ Cout, int ldc, int K) {
  __shared__ __align__(16) ushort As[2 * 128 * 64];
  __shared__ __align__(16) ushort Bs[2 * 128 * 64];
  f32x4 acc[4][2] = {};
  int bx, by;
  xcd_swz(bx, by);
  int m0 = by * 128, n0 = bx * 128;
  gemm_main(A, lda, Bt, ldb, K, m0, n0, As, Bs, acc);
  int lane = threadIdx.x & 63, wid = threadIdx.x >> 6;
  int wr = wid >> 2, wc = wid & 3, fr = lane & 15, fq = lane >> 4;
#pragma unroll
  for (int m = 0; m < 4; ++m) {
    int gm = m0 + wr * 64 + m * 16 + fq * 4;
#pragma unroll
    for (int n = 0; n < 2; ++n) {
      int gn = n0 + wc * 32 + n * 16 + fr;
      float bsv = bias[gn];
#pragma unroll
      for (int j = 0; j < 4; ++j) {
        int row = gm + j;
        float v = acc[m][n][j] + bsv;
        if constexpr (HASRES) v += res[(size_t)row * ldc + gn];
        if constexpr (RELU) v = fmaxf(v, 0.f);
        if constexpr (OUTBF16)
          ((ushort*)Cout)[(size_t)row * ldc + gn] = f2bf(v);
        else
          ((float*)Cout)[(size_t)row * ldc + gn] = v;
      }
    }
  }
}

// ---------------- MFMA flash attention (pair-balanced + l-via-MFMA) --------
// grid (8, 64): block handles q-tiles {i, 15-i}. Head-locality XCD swizzle:
// flat%8 selects XCD-stable head group (all 8 q-tile blocks of a head land
// on one XCD -> K/V L2-resident). l via ones-column MFMA.
constexpr int QB = 128, KVB = 64;
__global__ __launch_bounds__(512) void attn_kernel(const ushort* __restrict__ Qb,
                                                   const ushort* __restrict__ Kb,
                                                   const ushort* __restrict__ Vt,
                                                   ushort* __restrict__ att) {
  __shared__ __align__(16) ushort Klds[2][64 * 64];
  __shared__ __align__(16) ushort Vlds[2][64 * 64];
  __shared__ __align__(16) ushort Plds[8][16 * 64];
  int tid = threadIdx.x, wid = tid >> 6, lane = tid & 63;
  int fr = lane & 15, fq = lane >> 4;
  // head-locality remap: xcd = flat%8; heads {xcd, xcd+8, ...} -> same XCD;
  // q-tile index = seq%8. Bijective on [0,512).
  int flat = blockIdx.x + blockIdx.y * 8;
  int xcd = flat & 7, seq = flat >> 3;
  int bh = xcd + ((seq >> 3) << 3);
  int qx = seq & 7;
  int bb = bh >> 4, hh = bh & 15;
  const ushort* qkbase = Qb + ((size_t)bb * Tt) * Cc + hh * HSz;
  const ushort* Kbase = Kb + ((size_t)bb * Tt) * Cc + hh * HSz;
  const ushort* Vbase = Vt + ((size_t)(bb * Hh + hh)) * HSz * Tt;
  int srow = tid >> 3;
  int ssw = ((tid & 7) << 3) ^ ((srow & 7) << 3);
  bf16x8 vones;
#pragma unroll
  for (int i = 0; i < 8; ++i) vones[i] = (short)0x3F80;  // bf16 1.0

#pragma unroll 1
  for (int pass = 0; pass < 2; ++pass) {
    int qt = pass ? (Tt / QB - 1 - qx) : qx;
    int q0 = qt * QB;
    int q0w = q0 + wid * 16;

    bf16x8 Qreg[2];
#pragma unroll
    for (int d2 = 0; d2 < 2; ++d2)
      Qreg[d2] = *(const bf16x8*)(qkbase + (size_t)(q0w + fr) * Cc + d2 * 32 + fq * 8);
    f32x4 Oa[4] = {};
    f32x4 Ol = {};  // l in O-layout: Ol[j] = l(q = fq*4+j)
    float mrow = -1e30f;
    int nt = q0 / KVB + 2;

    __syncthreads();  // protect buf0 from previous pass's readers
    gload16(Kbase + (size_t)srow * Cc + ssw, (char*)Klds[0] + wid * 1024);
    gload16(Vbase + (size_t)srow * Tt + ssw, (char*)Vlds[0] + wid * 1024);

#pragma unroll 1
    for (int kt = 0; kt < nt; ++kt) {
      int t0 = kt * KVB;
      int c = kt & 1;
      __syncthreads();  // tile kt landed (implicit vmcnt(0)); WAR for buf c^1
      if (kt + 1 < nt) {
        int t0n = t0 + KVB;
        gload16(Kbase + (size_t)(t0n + srow) * Cc + ssw,
                (char*)Klds[c ^ 1] + wid * 1024);
        gload16(Vbase + (size_t)srow * Tt + t0n + ssw,
                (char*)Vlds[c ^ 1] + wid * 1024);
      }
      if (q0w + 15 < t0) continue;  // wave fully masked

      const char* Kc = (const char*)Klds[c];
      const char* Vc = (const char*)Vlds[c];
      bf16x8 kf[4][2];
#pragma unroll
      for (int ks = 0; ks < 4; ++ks)
#pragma unroll
        for (int d2 = 0; d2 < 2; ++d2) {
          int row = ks * 16 + fr;
          int off = (d2 * 64 + fq * 16) ^ ((row & 7) << 4);
          kf[ks][d2] = *(const bf16x8*)(Kc + row * 128 + off);
        }
      f32x4 accs[4] = {};
      __builtin_amdgcn_s_setprio(1);
#pragma unroll
      for (int ks = 0; ks < 4; ++ks) {
        accs[ks] = __builtin_amdgcn_mfma_f32_16x16x32_bf16(
            kf[ks][0], Qreg[0], accs[ks], 0, 0, 0);
        accs[ks] = __builtin_amdgcn_mfma_f32_16x16x32_bf16(
            kf[ks][1], Qreg[1], accs[ks], 0, 0, 0);
      }
      __builtin_amdgcn_s_setprio(0);

      float sv[4][4];
      if (t0 + 63 <= q0w) {
#pragma unroll
        for (int ks = 0; ks < 4; ++ks)
#pragma unroll
          for (int j = 0; j < 4; ++j) sv[ks][j] = accs[ks][j];
      } else {
        int qg = q0w + fr;
#pragma unroll
        for (int ks = 0; ks < 4; ++ks)
#pragma unroll
          for (int j = 0; j < 4; ++j) {
            int kg = t0 + ks * 16 + fq * 4 + j;
            sv[ks][j] = (kg <= qg) ? accs[ks][j] : -1e30f;
          }
      }
      // depth-4 max tree
      float m0a = fmaxf(fmaxf(sv[0][0], sv[0][1]), fmaxf(sv[0][2], sv[0][3]));
      float m1a = fmaxf(fmaxf(sv[1][0], sv[1][1]), fmaxf(sv[1][2], sv[1][3]));
      float m2a = fmaxf(fmaxf(sv[2][0], sv[2][1]), fmaxf(sv[2][2], sv[2][3]));
      float m3a = fmaxf(fmaxf(sv[3][0], sv[3][1]), fmaxf(sv[3][2], sv[3][3]));
      float vmax = fmaxf(fmaxf(m0a, m1a), fmaxf(m2a, m3a));

      float mnew = mrow;
      if (!__all(vmax <= mrow + 11.0f)) {
        float rmax = fmaxf(vmax, __shfl_xor(vmax, 16));
        rmax = fmaxf(rmax, __shfl_xor(rmax, 32));
        mnew = fmaxf(mrow, rmax);
        float sf = exp2f(mrow - mnew);
        mrow = mnew;
#pragma unroll
        for (int j = 0; j < 4; ++j) {
          float sfo = __shfl(sf, fq * 4 + j);
          Ol[j] *= sfo;
#pragma unroll
          for (int ds = 0; ds < 4; ++ds) Oa[ds][j] *= sfo;
        }
      }
      char* pbase = (char*)Plds[wid] + fr * 128;
#pragma unroll
      for (int ks = 0; ks < 4; ++ks) {
        float p0 = exp2f(sv[ks][0] - mnew);
        float p1 = exp2f(sv[ks][1] - mnew);
        float p2 = exp2f(sv[ks][2] - mnew);
        float p3 = exp2f(sv[ks][3] - mnew);
        uint2 pw = {cvtpk_bf16(p0, p1), cvtpk_bf16(p2, p3)};
        int off = (ks * 32 + fq * 8) ^ ((fr & 7) << 4);
        *(uint2*)(pbase + off) = pw;
      }

      bf16x8 vf[4][2];
#pragma unroll
      for (int ds = 0; ds < 4; ++ds)
#pragma unroll
        for (int k2 = 0; k2 < 2; ++k2) {
          int row = ds * 16 + fr;
          int off = (k2 * 64 + fq * 16) ^ ((row & 7) << 4);
          vf[ds][k2] = *(const bf16x8*)(Vc + row * 128 + off);
        }
      bf16x8 pf[2];
#pragma unroll
      for (int k2 = 0; k2 < 2; ++k2) {
        int off = (k2 * 64 + fq * 16) ^ ((fr & 7) << 4);
        pf[k2] = *(const bf16x8*)((const char*)Plds[wid] + fr * 128 + off);
      }
      __builtin_amdgcn_s_setprio(1);
#pragma unroll
      for (int ds = 0; ds < 4; ++ds) {
        Oa[ds] = __builtin_amdgcn_mfma_f32_16x16x32_bf16(
            pf[0], vf[ds][0], Oa[ds], 0, 0, 0);
        Oa[ds] = __builtin_amdgcn_mfma_f32_16x16x32_bf16(
            pf[1], vf[ds][1], Oa[ds], 0, 0, 0);
      }
      // l += sum_k P via ones-column MFMA (matrix pipe, no VALU)
      Ol = __builtin_amdgcn_mfma_f32_16x16x32_bf16(pf[0], vones, Ol, 0, 0, 0);
      Ol = __builtin_amdgcn_mfma_f32_16x16x32_bf16(pf[1], vones, Ol, 0, 0, 0);
      __builtin_amdgcn_s_setprio(0);
    }

    // ---- epilogue: shuffle-free (Ol[j] = l for q = fq*4+j) ----
#pragma unroll
    for (int j = 0; j < 4; ++j) {
      float lo = 1.f / Ol[j];
      int qg = q0w + fq * 4 + j;
      ushort* orow = att + (size_t)(bb * Tt + qg) * Cc + hh * HSz;
#pragma unroll
      for (int ds = 0; ds < 4; ++ds)
        orow[ds * 16 + fr] = f2bf(Oa[ds][j] * lo);
    }
  }
}

extern "C" void kernel_launch(void* const* d_in, const int* in_sizes, int n_in,
                              void* d_out, int out_size, void* d_ws,
                              size_t ws_size, hipStream_t stream) {
  const float* x = (const float*)d_in[0];
  const float* wq = (const float*)d_in[1];
  const float* bq = (const float*)d_in[2];
  const float* wk = (const float*)d_in[3];
  const float* bk = (const float*)d_in[4];
  const float* wv = (const float*)d_in[5];
  const float* bv = (const float*)d_in[6];
  const float* wp = (const float*)d_in[7];
  const float* bp = (const float*)d_in[8];
  const float* w1 = (const float*)d_in[9];
  const float* b1 = (const float*)d_in[10];
  const float* w2 = (const float*)d_in[11];
  const float* b2 = (const float*)d_in[12];
  const float* g1 = (const float*)d_in[13];
  const float* be1 = (const float*)d_in[14];
  const float* g2 = (const float*)d_in[15];
  const float* be2 = (const float*)d_in[16];
  float* out = (float*)d_out;

  ushort* Qb = (ushort*)d_ws;                 // [8192][1024]
  ushort* Kb = Qb + (size_t)8388608;          // [8192][1024]
  ushort* Vt = Kb + (size_t)8388608;          // [4][16][64][2048]
  ushort* att = Vt + (size_t)8388608;         // [8192][1024]
  ushort* ffh = Qb;                           // [8192][4096] overlay
  ushort* h1b = att + (size_t)8388608;        // LN1/LN2 out
  float* x2 = (float*)(h1b + (size_t)8388608);
  ushort* wqkvT = (ushort*)(x2 + (size_t)8388608);  // [3072][1024]
  ushort* wpT = wqkvT + (size_t)3145728;            // [1024][1024]
  ushort* w1T = wpT + (size_t)1048576;              // [4096][1024]
  ushort* w2T = w1T + (size_t)4194304;              // [1024][4096]
  float* bqkv = (float*)(w2T + (size_t)4194304);    // [3072]

  // 0) weight prep + LN1 in one kernel (12300 + 8192 blocks)
  prep_kernel<<<dim3(20492), 256, 0, stream>>>(wq, wk, wv, wp, w1, w2, bq, bk,
                                               bv, wqkvT, wpT, w1T, w2T, bqkv,
                                               x, g1, be1, h1b);
  // 2) Q,K,Vt = h1b @ WqkvT^T + bqkv  (256x192 3-phase — grid 16x32)
  gemm192_qkv<<<dim3(16, 32), 512, 0, stream>>>(h1b, wqkvT, bqkv, Qb, Kb, Vt);
  // 3) att = causal_softmax(Q K^T) V  (pair-balanced, head-XCD swizzle)
  attn_kernel<<<dim3(Tt / QB / 2, Bb * Hh), 512, 0, stream>>>(Qb, Kb, Vt, att);
  // 4) x2 = x + att @ wp + bp  (128^2 ring)
  gemm_bf16<false, true, false><<<dim3(8, 64), 512, 0, stream>>>(
      att, 1024, wpT, 1024, bp, x, x2, 1024, 1024);
  // 5) h2b = LN(x2)
  ln_kernel<<<dim3(Mrows), 256, 0, stream>>>(x2, g2, be2, h1b);
  // 6) ffh = relu(h2b @ w1 + b1)  (256^2 4-phase — grid 16x32)
  gemm256_relu<<<dim3(16, 32), 512, 0, stream>>>(h1b, w1T, b1, ffh, 4096);
  // 7) out = x2 + ffh @ w2 + b2  (128^2 ring)
  gemm_bf16<false, true, false><<<dim3(8, 64), 512, 0, stream>>>(
      ffh, 4096, w2T, 4096, b2, x2, out, 1024, 4096);
}

// Round 20
// 331.097 us; speedup vs baseline: 1.0292x; 1.0095x over previous
//
#include <hip/hip_runtime.h>

// Transformer block. Round 19: attn — 2 KV-tiles per barrier interval
// (4-slot K/V ring; stage kt+2,kt+3 after one barrier; compute kt,kt+1
// back-to-back). Barriers/drains halve; LDS 80 KB (grid = exactly 2
// blocks/CU so residency unaffected). Head-XCD swizzle + l-via-MFMA kept.
// Everything else frozen at round-18 config.
//
// Workspace (~136 MiB): [Q|K|Vt|att] <- ffh overlay; [h1b][x2][weights][bqkv]

constexpr int Bb = 4, Tt = 2048, Cc = 1024, Hh = 16, HSz = 64, Ff = 4096;
constexpr int Mrows = Bb * Tt;  // 8192

typedef __attribute__((ext_vector_type(8))) short bf16x8;
typedef __attribute__((ext_vector_type(4))) float f32x4;

__device__ __forceinline__ ushort f2bf(float f) {
  uint u = __builtin_bit_cast(uint, f);
  uint r = (u + 0x7fffu + ((u >> 16) & 1u)) >> 16;
  return (ushort)r;
}
__device__ __forceinline__ float bf2f(ushort s) {
  return __builtin_bit_cast(float, ((uint)s) << 16);
}
__device__ __forceinline__ uint cvtpk_bf16(float lo, float hi) {
  uint r;
  asm("v_cvt_pk_bf16_f32 %0, %1, %2" : "=v"(r) : "v"(lo), "v"(hi));
  return r;
}
__device__ __forceinline__ void gload16(const void* g, void* l) {
  __builtin_amdgcn_global_load_lds(
      (const __attribute__((address_space(1))) void*)g,
      (__attribute__((address_space(3))) void*)l, 16, 0, 0);
}
#define VMCNT(n) asm volatile("s_waitcnt vmcnt(" #n ")" ::: "memory")
#define LGKM0                                          \
  do {                                                 \
    asm volatile("s_waitcnt lgkmcnt(0)" ::: "memory"); \
    __builtin_amdgcn_sched_barrier(0);                 \
  } while (0)
#define BARRIER __builtin_amdgcn_s_barrier()

// ---------------- LayerNorm body: fp32 in, bf16 out ----------------
__device__ __forceinline__ void ln_body(const float* __restrict__ x,
                                        const float* __restrict__ g,
                                        const float* __restrict__ b,
                                        ushort* __restrict__ out, int row) {
  const float* xr = x + (size_t)row * Cc;
  int c4 = threadIdx.x * 4;
  float4 v = *(const float4*)(xr + c4);
  float s1 = v.x + v.y + v.z + v.w;
  float s2 = v.x * v.x + v.y * v.y + v.z * v.z + v.w * v.w;
#pragma unroll
  for (int off = 32; off >= 1; off >>= 1) {
    s1 += __shfl_xor(s1, off);
    s2 += __shfl_xor(s2, off);
  }
  __shared__ float red[8];
  int wid = threadIdx.x >> 6, lane = threadIdx.x & 63;
  if (lane == 0) { red[wid] = s1; red[4 + wid] = s2; }
  __syncthreads();
  float t1 = red[0] + red[1] + red[2] + red[3];
  float t2 = red[4] + red[5] + red[6] + red[7];
  float mu = t1 * (1.0f / Cc);
  float var = t2 * (1.0f / Cc) - mu * mu;
  float rs = rsqrtf(var + 1e-5f);
  float4 gv = *(const float4*)(g + c4);
  float4 bv = *(const float4*)(b + c4);
  ushort4 o;
  o.x = f2bf((v.x - mu) * rs * gv.x + bv.x);
  o.y = f2bf((v.y - mu) * rs * gv.y + bv.y);
  o.z = f2bf((v.z - mu) * rs * gv.z + bv.z);
  o.w = f2bf((v.w - mu) * rs * gv.w + bv.w);
  *(ushort4*)(out + (size_t)row * Cc + c4) = o;
}

__global__ __launch_bounds__(256) void ln_kernel(const float* __restrict__ x,
                                                 const float* __restrict__ g,
                                                 const float* __restrict__ b,
                                                 ushort* __restrict__ out) {
  ln_body(x, g, b, out, blockIdx.x);
}

// ---------------- Transpose-cast fp32 [R][C] -> bf16 [C][R] ----------------
__device__ __forceinline__ void tcast_body(const float* __restrict__ src,
                                           ushort* __restrict__ dst, int ldS,
                                           int ldD, int r0, int c0) {
  __shared__ float t[32][33];
  int c = threadIdx.x & 31, r8 = threadIdx.x >> 5;
#pragma unroll
  for (int i = 0; i < 4; ++i) {
    int r = r8 + i * 8;
    t[r][c] = src[(size_t)(r0 + r) * ldS + c0 + c];
  }
  __syncthreads();
#pragma unroll
  for (int i = 0; i < 4; ++i) {
    int rr = r8 + i * 8;
    dst[(size_t)(c0 + rr) * ldD + r0 + c] = f2bf(t[c][rr]);
  }
}

// Fused prep: qkv tcast (3072) | wp (1024) | w1 (4096) | w2 (4096) |
// bias-concat (12) | LN1 rows (8192). Branch is block-uniform.
__global__ __launch_bounds__(256) void prep_kernel(
    const float* __restrict__ wq, const float* __restrict__ wk,
    const float* __restrict__ wv, const float* __restrict__ wp,
    const float* __restrict__ w1, const float* __restrict__ w2,
    const float* __restrict__ bq, const float* __restrict__ bk,
    const float* __restrict__ bv, ushort* __restrict__ wqkvT,
    ushort* __restrict__ wpT, ushort* __restrict__ w1T,
    ushort* __restrict__ w2T, float* __restrict__ bqkv,
    const float* __restrict__ x, const float* __restrict__ g1,
    const float* __restrict__ be1, ushort* __restrict__ h1b) {
  int id = blockIdx.x;
  if (id < 3072) {
    int z = id >> 6, rem = id & 63;
    int zz = z >> 4, h = z & 15;
    const float* src =
        (zz == 0 ? wq : (zz == 1 ? wk : wv)) + (size_t)h * Cc * HSz;
    ushort* d = wqkvT + (size_t)(zz * 1024 + h * 64) * 1024;
    tcast_body(src, d, HSz, Cc, (rem & 31) * 32, (rem >> 5) * 32);
  } else if (id < 4096) {
    int rem = id - 3072;  // 32x32
    tcast_body(wp, wpT, 1024, 1024, (rem & 31) * 32, (rem >> 5) * 32);
  } else if (id < 8192) {
    int rem = id - 4096;  // (32,128)
    tcast_body(w1, w1T, 4096, 1024, (rem & 31) * 32, (rem >> 5) * 32);
  } else if (id < 12288) {
    int rem = id - 8192;  // (128,32)
    tcast_body(w2, w2T, 1024, 4096, (rem & 127) * 32, (rem >> 7) * 32);
  } else if (id < 12300) {
    int i = (id - 12288) * 256 + threadIdx.x;
    bqkv[i] = i < 1024 ? bq[i] : (i < 2048 ? bk[i - 1024] : bv[i - 2048]);
  } else {
    ln_body(x, g1, be1, h1b, id - 12300);  // LN1 fused
  }
}

// XCD-chunked bijective block swizzle (all grids %8 == 0).
__device__ __forceinline__ void xcd_swz(int& bx, int& by) {
  int bid = blockIdx.x + blockIdx.y * gridDim.x;
  int cpx = (gridDim.x * gridDim.y) >> 3;
  int id = (bid & 7) * cpx + (bid >> 3);
  bx = id % gridDim.x;
  by = id / gridDim.x;
}

// ============ 256x256 tile, BK=64, 8 waves (2Mx4N), 4-phase K-loop =========
template <int MH, int NH>
__device__ __forceinline__ void mfma16(f32x4 (&acc)[8][4], bf16x8 (&a)[4][2],
                                       bf16x8 (&b)[2][2]) {
#pragma unroll
  for (int m = 0; m < 4; ++m)
#pragma unroll
    for (int n = 0; n < 2; ++n)
#pragma unroll
      for (int kk = 0; kk < 2; ++kk)
        acc[MH * 4 + m][NH * 2 + n] = __builtin_amdgcn_mfma_f32_16x16x32_bf16(
            a[m][kk], b[n][kk], acc[MH * 4 + m][NH * 2 + n], 0, 0, 0);
}

__device__ __forceinline__ void gemm256_main(const ushort* __restrict__ A,
                                             const ushort* __restrict__ Bt,
                                             int m0, int n0,
                                             ushort* __restrict__ As,
                                             ushort* __restrict__ Bs,
                                             f32x4 (&acc)[8][4]) {
  constexpr int NKT = 16;  // K = 1024
  int tid = threadIdx.x, wid = tid >> 6, lane = tid & 63;
  int wr = wid >> 2, wc = wid & 3, fr = lane & 15, fq = lane >> 4;
  const ushort* Ag = A + (size_t)m0 * 1024;
  const ushort* Bg = Bt + (size_t)n0 * 1024;
  int r0 = tid >> 3, r1 = 64 + (tid >> 3);
  int sc = ((tid & 7) ^ ((tid >> 3) & 7)) << 3;

  auto stage = [&](int ktn, int h, int ns) {  // h: 0=A-h0 1=A-h1 2=B-h0 3=B-h1
    const ushort* g = (h < 2) ? Ag : Bg;
    ushort* l = ((h < 2) ? As : Bs) + ns * 16384 + (h & 1) * 8192;
    int kcol = ktn * 64, rbase = (h & 1) * 128;
    gload16(g + (size_t)(rbase + r0) * 1024 + kcol + sc, l + (size_t)wid * 512);
    gload16(g + (size_t)(rbase + r1) * 1024 + kcol + sc,
            l + (size_t)(512 + wid * 64) * 8);
  };
  auto readA = [&](int slot, int mh, bf16x8 (&a)[4][2]) {
#pragma unroll
    for (int m = 0; m < 4; ++m) {
      int row = wr * 128 + mh * 64 + m * 16 + fr;
#pragma unroll
      for (int kk = 0; kk < 2; ++kk)
        a[m][kk] = *(const bf16x8*)&As[slot * 16384 + row * 64 +
                                       (((kk * 4 + fq) ^ (row & 7)) << 3)];
    }
  };
  auto readB = [&](int slot, int nh, bf16x8 (&b)[2][2]) {
#pragma unroll
    for (int n = 0; n < 2; ++n) {
      int row = wc * 64 + nh * 32 + n * 16 + fr;
#pragma unroll
      for (int kk = 0; kk < 2; ++kk)
        b[n][kk] = *(const bf16x8*)&Bs[slot * 16384 + row * 64 +
                                       (((kk * 4 + fq) ^ (row & 7)) << 3)];
    }
  };

  stage(0, 0, 0); stage(0, 1, 0); stage(0, 2, 0); stage(0, 3, 0);
  VMCNT(0);
  BARRIER;

  bf16x8 a[4][2], b0[2][2], b1[2][2];
#pragma unroll 1
  for (int kt = 0; kt < NKT; ++kt) {
    int slot = kt & 1, ns = slot ^ 1;
    bool st = (kt + 1 < NKT);
    readA(slot, 0, a);
    readB(slot, 0, b0);
    if (st) { stage(kt + 1, 0, ns); stage(kt + 1, 2, ns); }
    BARRIER;
    LGKM0;
    __builtin_amdgcn_s_setprio(1);
    mfma16<0, 0>(acc, a, b0);
    __builtin_amdgcn_s_setprio(0);
    BARRIER;
    readB(slot, 1, b1);
    if (st) { stage(kt + 1, 1, ns); stage(kt + 1, 3, ns); }
    BARRIER;
    LGKM0;
    __builtin_amdgcn_s_setprio(1);
    mfma16<0, 1>(acc, a, b1);
    __builtin_amdgcn_s_setprio(0);
    BARRIER;
    readA(slot, 1, a);
    BARRIER;
    LGKM0;
    __builtin_amdgcn_s_setprio(1);
    mfma16<1, 0>(acc, a, b0);
    __builtin_amdgcn_s_setprio(0);
    BARRIER;
    __builtin_amdgcn_s_setprio(1);
    mfma16<1, 1>(acc, a, b1);
    __builtin_amdgcn_s_setprio(0);
    VMCNT(0);
    BARRIER;
  }
}

// FFN1: ffh = relu(h1b @ w1T^T + b1), bf16 out [8192][4096]
__global__ __launch_bounds__(512, 2) void gemm256_relu(
    const ushort* __restrict__ A, const ushort* __restrict__ Bt,
    const float* __restrict__ bias, ushort* __restrict__ Cout, int ldc) {
  __shared__ __align__(16) ushort As[2 * 256 * 64];
  __shared__ __align__(16) ushort Bs[2 * 256 * 64];
  f32x4 acc[8][4] = {};
  int bx, by;
  xcd_swz(bx, by);
  int m0 = by * 256, n0 = bx * 256;
  gemm256_main(A, Bt, m0, n0, As, Bs, acc);
  int lane = threadIdx.x & 63, wid = threadIdx.x >> 6;
  int wr = wid >> 2, wc = wid & 3, fr = lane & 15, fq = lane >> 4;
#pragma unroll
  for (int i = 0; i < 8; ++i) {
    int gm = m0 + wr * 128 + (i >> 2) * 64 + (i & 3) * 16 + fq * 4;
#pragma unroll
    for (int j2 = 0; j2 < 4; ++j2) {
      int gn = n0 + wc * 64 + (j2 >> 1) * 32 + (j2 & 1) * 16 + fr;
      float bsv = bias[gn];
#pragma unroll
      for (int j = 0; j < 4; ++j)
        Cout[(size_t)(gm + j) * ldc + gn] = f2bf(fmaxf(acc[i][j2][j] + bsv, 0.f));
    }
  }
}

// ===== QKV: 256Mx192N tile, BK=64, 8 waves (2Mx4N), 3-phase K-loop ========
__global__ __launch_bounds__(512, 2) void gemm192_qkv(
    const ushort* __restrict__ A, const ushort* __restrict__ Bt,
    const float* __restrict__ bias, ushort* __restrict__ q,
    ushort* __restrict__ k, ushort* __restrict__ vt) {
  __shared__ __align__(16) ushort As[2 * 256 * 64];
  __shared__ __align__(16) ushort Bs[2 * 192 * 64];
  f32x4 acc[8][3] = {};
  int bx, by;
  xcd_swz(bx, by);
  int m0 = by * 256, n0 = bx * 192;
  int tid = threadIdx.x, wid = tid >> 6, lane = tid & 63;
  int wr = wid >> 2, wc = wid & 3, fr = lane & 15, fq = lane >> 4;
  const ushort* Ag = A + (size_t)m0 * 1024;
  const ushort* Bg = Bt + (size_t)n0 * 1024;
  int r0 = tid >> 3;
  int sc = ((tid & 7) ^ ((tid >> 3) & 7)) << 3;
  constexpr int NKT = 16;  // K = 1024

  auto stageA = [&](int ktn, int c, int ns) {
    ushort* l = As + ns * 16384 + c * 4096;
    gload16(Ag + (size_t)(c * 64 + r0) * 1024 + ktn * 64 + sc,
            l + (size_t)wid * 512);
  };
  auto stageB = [&](int ktn, int c, int ns) {
    ushort* l = Bs + ns * 12288 + c * 4096;
    gload16(Bg + (size_t)(c * 64 + r0) * 1024 + ktn * 64 + sc,
            l + (size_t)wid * 512);
  };
  auto readA = [&](int slot, int mh, bf16x8 (&a)[4][2]) {
#pragma unroll
    for (int m = 0; m < 4; ++m) {
      int row = wr * 128 + mh * 64 + m * 16 + fr;
#pragma unroll
      for (int kk = 0; kk < 2; ++kk)
        a[m][kk] = *(const bf16x8*)&As[slot * 16384 + row * 64 +
                                       (((kk * 4 + fq) ^ (row & 7)) << 3)];
    }
  };
  auto readB = [&](int slot, int nh, bf16x8 (&b)[2]) {
    int row = wc * 48 + nh * 16 + fr;
#pragma unroll
    for (int kk = 0; kk < 2; ++kk)
      b[kk] = *(const bf16x8*)&Bs[slot * 12288 + row * 64 +
                                  (((kk * 4 + fq) ^ (row & 7)) << 3)];
  };
  auto mfma16n = [&](int nh, bf16x8 (&a0)[4][2], bf16x8 (&a1)[4][2],
                     bf16x8 (&b)[2]) {
#pragma unroll
    for (int m = 0; m < 4; ++m)
#pragma unroll
      for (int kk = 0; kk < 2; ++kk)
        acc[m][nh] = __builtin_amdgcn_mfma_f32_16x16x32_bf16(
            a0[m][kk], b[kk], acc[m][nh], 0, 0, 0);
#pragma unroll
    for (int m = 0; m < 4; ++m)
#pragma unroll
      for (int kk = 0; kk < 2; ++kk)
        acc[4 + m][nh] = __builtin_amdgcn_mfma_f32_16x16x32_bf16(
            a1[m][kk], b[kk], acc[4 + m][nh], 0, 0, 0);
  };

  stageA(0, 0, 0); stageA(0, 1, 0); stageA(0, 2, 0); stageA(0, 3, 0);
  stageB(0, 0, 0); stageB(0, 1, 0); stageB(0, 2, 0);
  VMCNT(0);
  BARRIER;

  bf16x8 a0[4][2], a1[4][2], b0[2], b1[2], b2[2];
#pragma unroll 1
  for (int kt = 0; kt < NKT; ++kt) {
    int slot = kt & 1, ns = slot ^ 1;
    bool st = (kt + 1 < NKT);
    readA(slot, 0, a0);
    readA(slot, 1, a1);
    readB(slot, 0, b0);
    if (st) { stageA(kt + 1, 0, ns); stageA(kt + 1, 1, ns); stageB(kt + 1, 0, ns); }
    BARRIER;
    LGKM0;
    __builtin_amdgcn_s_setprio(1);
    mfma16n(0, a0, a1, b0);
    __builtin_amdgcn_s_setprio(0);
    BARRIER;
    readB(slot, 1, b1);
    if (st) { stageA(kt + 1, 2, ns); stageA(kt + 1, 3, ns); stageB(kt + 1, 1, ns); }
    BARRIER;
    LGKM0;
    __builtin_amdgcn_s_setprio(1);
    mfma16n(1, a0, a1, b1);
    __builtin_amdgcn_s_setprio(0);
    BARRIER;
    readB(slot, 2, b2);
    if (st) { stageB(kt + 1, 2, ns); }
    BARRIER;
    LGKM0;
    __builtin_amdgcn_s_setprio(1);
    mfma16n(2, a0, a1, b2);
    __builtin_amdgcn_s_setprio(0);
    VMCNT(0);
    BARRIER;
  }

  const float qscale = 1.4426950408889634f / 32.0f;  // log2e * C^-0.5
#pragma unroll
  for (int i = 0; i < 8; ++i) {
    int gm = m0 + wr * 128 + (i >> 2) * 64 + (i & 3) * 16 + fq * 4;
#pragma unroll
    for (int nh = 0; nh < 3; ++nh) {
      int gn = n0 + wc * 48 + nh * 16 + fr;
      float bsv = bias[gn];
      if (gn < 1024) {
#pragma unroll
        for (int j = 0; j < 4; ++j)
          q[(size_t)(gm + j) * 1024 + gn] = f2bf((acc[i][nh][j] + bsv) * qscale);
      } else if (gn < 2048) {
        int col = gn - 1024;
#pragma unroll
        for (int j = 0; j < 4; ++j)
          k[(size_t)(gm + j) * 1024 + col] = f2bf(acc[i][nh][j] + bsv);
      } else {
        int dd = gn - 2048, h = dd >> 6, d = dd & 63;
        int bbr = gm >> 11, t = gm & 2047;
        ushort4 pw = {f2bf(acc[i][nh][0] + bsv), f2bf(acc[i][nh][1] + bsv),
                      f2bf(acc[i][nh][2] + bsv), f2bf(acc[i][nh][3] + bsv)};
        *(ushort4*)&vt[(((size_t)(bbr * 16 + h)) * 64 + d) * 2048 + t] = pw;
      }
    }
  }
}

// -------- 128x128 bf16 GEMM, 2-slot ring + issue-after-barrier prefetch ---
__device__ __forceinline__ void gemm_main(const ushort* __restrict__ A, int lda,
                                          const ushort* __restrict__ Bt, int ldb,
                                          int K, int m0, int n0,
                                          ushort* __restrict__ As,
                                          ushort* __restrict__ Bs,
                                          f32x4 (&acc)[4][2]) {
  int tid = threadIdx.x, wid = tid >> 6, lane = tid & 63;
  int wr = wid >> 2, wc = wid & 3, fr = lane & 15, fq = lane >> 4;
  const ushort* Ag = A + (size_t)m0 * lda;
  const ushort* Bg = Bt + (size_t)n0 * ldb;
  int NKT = K >> 6;
  auto stage = [&](int ktn, int sl) {
#pragma unroll
    for (int c = 0; c < 2; ++c) {
      int slot = c * 512 + tid;
      int row = slot >> 3, s = slot & 7;
      int sw = (s << 3) ^ ((row & 7) << 3);
      gload16(Ag + (size_t)row * lda + ktn * 64 + sw,
              As + sl * 8192 + (size_t)(c * 512 + wid * 64) * 8);
      gload16(Bg + (size_t)row * ldb + ktn * 64 + sw,
              Bs + sl * 8192 + (size_t)(c * 512 + wid * 64) * 8);
    }
  };

  stage(0, 0);  // prologue
#pragma unroll 1
  for (int kt = 0; kt < NKT; ++kt) {
    int c = kt & 1;
    __syncthreads();  // tile kt landed; WAR-safe for slot c^1
    if (kt + 1 < NKT) stage(kt + 1, c ^ 1);
    bf16x8 av[4][2], bv[2][2];
#pragma unroll
    for (int m = 0; m < 4; ++m) {
      int row = wr * 64 + m * 16 + fr;
#pragma unroll
      for (int ks = 0; ks < 2; ++ks)
        av[m][ks] = *(const bf16x8*)&As[c * 8192 + row * 64 +
                                        (((ks * 4 + fq) ^ (row & 7)) << 3)];
    }
#pragma unroll
    for (int n = 0; n < 2; ++n) {
      int row = wc * 32 + n * 16 + fr;
#pragma unroll
      for (int ks = 0; ks < 2; ++ks)
        bv[n][ks] = *(const bf16x8*)&Bs[c * 8192 + row * 64 +
                                        (((ks * 4 + fq) ^ (row & 7)) << 3)];
    }
    __builtin_amdgcn_s_setprio(1);
#pragma unroll
    for (int m = 0; m < 4; ++m)
#pragma unroll
      for (int n = 0; n < 2; ++n)
#pragma unroll
        for (int ks = 0; ks < 2; ++ks)
          acc[m][n] = __builtin_amdgcn_mfma_f32_16x16x32_bf16(
              av[m][ks], bv[n][ks], acc[m][n], 0, 0, 0);
    __builtin_amdgcn_s_setprio(0);
  }
}

template <bool RELU, bool HASRES, bool OUTBF16>
__global__ __launch_bounds__(512) void gemm_bf16(
    const ushort* __restrict__ A, int lda, const ushort* __restrict__ Bt,
    int ldb, const float* __restrict__ bias, const float* __restrict__ res,
    void* __restrict__ Cout, int ldc, int K) {
  __shared__ __align__(16) ushort As[2 * 128 * 64];
  __shared__ __align__(16) ushort Bs[2 * 128 * 64];
  f32x4 acc[4][2] = {};
  int bx, by;
  xcd_swz(bx, by);
  int m0 = by * 128, n0 = bx * 128;
  gemm_main(A, lda, Bt, ldb, K, m0, n0, As, Bs, acc);
  int lane = threadIdx.x & 63, wid = threadIdx.x >> 6;
  int wr = wid >> 2, wc = wid & 3, fr = lane & 15, fq = lane >> 4;
#pragma unroll
  for (int m = 0; m < 4; ++m) {
    int gm = m0 + wr * 64 + m * 16 + fq * 4;
#pragma unroll
    for (int n = 0; n < 2; ++n) {
      int gn = n0 + wc * 32 + n * 16 + fr;
      float bsv = bias[gn];
#pragma unroll
      for (int j = 0; j < 4; ++j) {
        int row = gm + j;
        float v = acc[m][n][j] + bsv;
        if constexpr (HASRES) v += res[(size_t)row * ldc + gn];
        if constexpr (RELU) v = fmaxf(v, 0.f);
        if constexpr (OUTBF16)
          ((ushort*)Cout)[(size_t)row * ldc + gn] = f2bf(v);
        else
          ((float*)Cout)[(size_t)row * ldc + gn] = v;
      }
    }
  }
}

// --- MFMA flash attention: head-XCD swizzle + 2 tiles per barrier ---------
// grid (8, 64): block handles q-tiles {i, 15-i}. 4-slot K/V ring: one
// __syncthreads per 2 KV-tiles (stage kt+2,kt+3 after barrier; compute
// kt, kt+1 back-to-back). l via ones-column MFMA; shuffle-free epilogue.
constexpr int QB = 128, KVB = 64;
__global__ __launch_bounds__(512) void attn_kernel(const ushort* __restrict__ Qb,
                                                   const ushort* __restrict__ Kb,
                                                   const ushort* __restrict__ Vt,
                                                   ushort* __restrict__ att) {
  __shared__ __align__(16) ushort Klds[4][64 * 64];
  __shared__ __align__(16) ushort Vlds[4][64 * 64];
  __shared__ __align__(16) ushort Plds[8][16 * 64];
  int tid = threadIdx.x, wid = tid >> 6, lane = tid & 63;
  int fr = lane & 15, fq = lane >> 4;
  // head-locality remap: xcd = flat%8; heads {xcd, xcd+8, ...} -> same XCD.
  int flat = blockIdx.x + blockIdx.y * 8;
  int xcd = flat & 7, seq = flat >> 3;
  int bh = xcd + ((seq >> 3) << 3);
  int qx = seq & 7;
  int bb = bh >> 4, hh = bh & 15;
  const ushort* qkbase = Qb + ((size_t)bb * Tt) * Cc + hh * HSz;
  const ushort* Kbase = Kb + ((size_t)bb * Tt) * Cc + hh * HSz;
  const ushort* Vbase = Vt + ((size_t)(bb * Hh + hh)) * HSz * Tt;
  int srow = tid >> 3;
  int ssw = ((tid & 7) << 3) ^ ((srow & 7) << 3);
  bf16x8 vones;
#pragma unroll
  for (int i = 0; i < 8; ++i) vones[i] = (short)0x3F80;  // bf16 1.0

  auto stageKV = [&](int ktn, int sl) {
    gload16(Kbase + (size_t)(ktn * KVB + srow) * Cc + ssw,
            (char*)Klds[sl] + wid * 1024);
    gload16(Vbase + (size_t)srow * Tt + ktn * KVB + ssw,
            (char*)Vlds[sl] + wid * 1024);
  };

#pragma unroll 1
  for (int pass = 0; pass < 2; ++pass) {
    int qt = pass ? (Tt / QB - 1 - qx) : qx;
    int q0 = qt * QB;
    int q0w = q0 + wid * 16;

    bf16x8 Qreg[2];
#pragma unroll
    for (int d2 = 0; d2 < 2; ++d2)
      Qreg[d2] = *(const bf16x8*)(qkbase + (size_t)(q0w + fr) * Cc + d2 * 32 + fq * 8);
    f32x4 Oa[4] = {};
    f32x4 Ol = {};  // l in O-layout: Ol[j] = l(q = fq*4+j)
    float mrow = -1e30f;
    int nt = q0 / KVB + 2;

    // per-tile compute body (round-18 logic, slot-parameterized)
    auto process = [&](int t0, int sl) {
      if (q0w + 15 < t0) return;  // wave fully masked
      const char* Kc = (const char*)Klds[sl];
      const char* Vc = (const char*)Vlds[sl];
      bf16x8 kf[4][2];
#pragma unroll
      for (int ks = 0; ks < 4; ++ks)
#pragma unroll
        for (int d2 = 0; d2 < 2; ++d2) {
          int row = ks * 16 + fr;
          int off = (d2 * 64 + fq * 16) ^ ((row & 7) << 4);
          kf[ks][d2] = *(const bf16x8*)(Kc + row * 128 + off);
        }
      f32x4 accs[4] = {};
      __builtin_amdgcn_s_setprio(1);
#pragma unroll
      for (int ks = 0; ks < 4; ++ks) {
        accs[ks] = __builtin_amdgcn_mfma_f32_16x16x32_bf16(
            kf[ks][0], Qreg[0], accs[ks], 0, 0, 0);
        accs[ks] = __builtin_amdgcn_mfma_f32_16x16x32_bf16(
            kf[ks][1], Qreg[1], accs[ks], 0, 0, 0);
      }
      __builtin_amdgcn_s_setprio(0);

      float sv[4][4];
      if (t0 + 63 <= q0w) {
#pragma unroll
        for (int ks = 0; ks < 4; ++ks)
#pragma unroll
          for (int j = 0; j < 4; ++j) sv[ks][j] = accs[ks][j];
      } else {
        int qg = q0w + fr;
#pragma unroll
        for (int ks = 0; ks < 4; ++ks)
#pragma unroll
          for (int j = 0; j < 4; ++j) {
            int kg = t0 + ks * 16 + fq * 4 + j;
            sv[ks][j] = (kg <= qg) ? accs[ks][j] : -1e30f;
          }
      }
      float m0a = fmaxf(fmaxf(sv[0][0], sv[0][1]), fmaxf(sv[0][2], sv[0][3]));
      float m1a = fmaxf(fmaxf(sv[1][0], sv[1][1]), fmaxf(sv[1][2], sv[1][3]));
      float m2a = fmaxf(fmaxf(sv[2][0], sv[2][1]), fmaxf(sv[2][2], sv[2][3]));
      float m3a = fmaxf(fmaxf(sv[3][0], sv[3][1]), fmaxf(sv[3][2], sv[3][3]));
      float vmax = fmaxf(fmaxf(m0a, m1a), fmaxf(m2a, m3a));

      float mnew = mrow;
      if (!__all(vmax <= mrow + 11.0f)) {
        float rmax = fmaxf(vmax, __shfl_xor(vmax, 16));
        rmax = fmaxf(rmax, __shfl_xor(rmax, 32));
        mnew = fmaxf(mrow, rmax);
        float sf = exp2f(mrow - mnew);
        mrow = mnew;
#pragma unroll
        for (int j = 0; j < 4; ++j) {
          float sfo = __shfl(sf, fq * 4 + j);
          Ol[j] *= sfo;
#pragma unroll
          for (int ds = 0; ds < 4; ++ds) Oa[ds][j] *= sfo;
        }
      }
      char* pbase = (char*)Plds[wid] + fr * 128;
#pragma unroll
      for (int ks = 0; ks < 4; ++ks) {
        float p0 = exp2f(sv[ks][0] - mnew);
        float p1 = exp2f(sv[ks][1] - mnew);
        float p2 = exp2f(sv[ks][2] - mnew);
        float p3 = exp2f(sv[ks][3] - mnew);
        uint2 pw = {cvtpk_bf16(p0, p1), cvtpk_bf16(p2, p3)};
        int off = (ks * 32 + fq * 8) ^ ((fr & 7) << 4);
        *(uint2*)(pbase + off) = pw;
      }

      bf16x8 pf[2];
#pragma unroll
      for (int k2 = 0; k2 < 2; ++k2) {
        int off = (k2 * 64 + fq * 16) ^ ((fr & 7) << 4);
        pf[k2] = *(const bf16x8*)((const char*)Plds[wid] + fr * 128 + off);
      }
      __builtin_amdgcn_s_setprio(1);
#pragma unroll
      for (int ds = 0; ds < 4; ++ds) {
        int row = ds * 16 + fr;
        bf16x8 vf0 = *(const bf16x8*)(Vc + row * 128 +
                                      ((0 * 64 + fq * 16) ^ ((row & 7) << 4)));
        bf16x8 vf1 = *(const bf16x8*)(Vc + row * 128 +
                                      ((1 * 64 + fq * 16) ^ ((row & 7) << 4)));
        Oa[ds] = __builtin_amdgcn_mfma_f32_16x16x32_bf16(pf[0], vf0, Oa[ds], 0, 0, 0);
        Oa[ds] = __builtin_amdgcn_mfma_f32_16x16x32_bf16(pf[1], vf1, Oa[ds], 0, 0, 0);
      }
      Ol = __builtin_amdgcn_mfma_f32_16x16x32_bf16(pf[0], vones, Ol, 0, 0, 0);
      Ol = __builtin_amdgcn_mfma_f32_16x16x32_bf16(pf[1], vones, Ol, 0, 0, 0);
      __builtin_amdgcn_s_setprio(0);
    };

    __syncthreads();  // protect slots from previous pass's readers
    // prologue: stage tiles 0,1 -> slots 0,1
    stageKV(0, 0);
    if (nt > 1) stageKV(1, 1);

#pragma unroll 1
    for (int kt = 0; kt < nt; kt += 2) {
      __syncthreads();  // tiles kt,kt+1 landed (implicit vmcnt(0) drain);
                        // WAR-safe for slots (kt+2)&3,(kt+3)&3 (readers of
                        // tiles kt-2,kt-1 finished before previous barrier)
      if (kt + 2 < nt) stageKV(kt + 2, (kt + 2) & 3);
      if (kt + 3 < nt) stageKV(kt + 3, (kt + 3) & 3);
      process(kt * KVB, kt & 3);
      if (kt + 1 < nt) process((kt + 1) * KVB, (kt + 1) & 3);
    }

    // ---- epilogue: shuffle-free (Ol[j] = l for q = fq*4+j) ----
#pragma unroll
    for (int j = 0; j < 4; ++j) {
      float lo = 1.f / Ol[j];
      int qg = q0w + fq * 4 + j;
      ushort* orow = att + (size_t)(bb * Tt + qg) * Cc + hh * HSz;
#pragma unroll
      for (int ds = 0; ds < 4; ++ds)
        orow[ds * 16 + fr] = f2bf(Oa[ds][j] * lo);
    }
  }
}

extern "C" void kernel_launch(void* const* d_in, const int* in_sizes, int n_in,
                              void* d_out, int out_size, void* d_ws,
                              size_t ws_size, hipStream_t stream) {
  const float* x = (const float*)d_in[0];
  const float* wq = (const float*)d_in[1];
  const float* bq = (const float*)d_in[2];
  const float* wk = (const float*)d_in[3];
  const float* bk = (const float*)d_in[4];
  const float* wv = (const float*)d_in[5];
  const float* bv = (const float*)d_in[6];
  const float* wp = (const float*)d_in[7];
  const float* bp = (const float*)d_in[8];
  const float* w1 = (const float*)d_in[9];
  const float* b1 = (const float*)d_in[10];
  const float* w2 = (const float*)d_in[11];
  const float* b2 = (const float*)d_in[12];
  const float* g1 = (const float*)d_in[13];
  const float* be1 = (const float*)d_in[14];
  const float* g2 = (const float*)d_in[15];
  const float* be2 = (const float*)d_in[16];
  float* out = (float*)d_out;

  ushort* Qb = (ushort*)d_ws;                 // [8192][1024]
  ushort* Kb = Qb + (size_t)8388608;          // [8192][1024]
  ushort* Vt = Kb + (size_t)8388608;          // [4][16][64][2048]
  ushort* att = Vt + (size_t)8388608;         // [8192][1024]
  ushort* ffh = Qb;                           // [8192][4096] overlay
  ushort* h1b = att + (size_t)8388608;        // LN1/LN2 out
  float* x2 = (float*)(h1b + (size_t)8388608);
  ushort* wqkvT = (ushort*)(x2 + (size_t)8388608);  // [3072][1024]
  ushort* wpT = wqkvT + (size_t)3145728;            // [1024][1024]
  ushort* w1T = wpT + (size_t)1048576;              // [4096][1024]
  ushort* w2T = w1T + (size_t)4194304;              // [1024][4096]
  float* bqkv = (float*)(w2T + (size_t)4194304);    // [3072]

  // 0) weight prep + LN1 in one kernel (12300 + 8192 blocks)
  prep_kernel<<<dim3(20492), 256, 0, stream>>>(wq, wk, wv, wp, w1, w2, bq, bk,
                                               bv, wqkvT, wpT, w1T, w2T, bqkv,
                                               x, g1, be1, h1b);
  // 2) Q,K,Vt = h1b @ WqkvT^T + bqkv  (256x192 3-phase — grid 16x32)
  gemm192_qkv<<<dim3(16, 32), 512, 0, stream>>>(h1b, wqkvT, bqkv, Qb, Kb, Vt);
  // 3) att = causal_softmax(Q K^T) V  (pair-balanced, head-XCD, 2-tile step)
  attn_kernel<<<dim3(Tt / QB / 2, Bb * Hh), 512, 0, stream>>>(Qb, Kb, Vt, att);
  // 4) x2 = x + att @ wp + bp  (128^2 ring)
  gemm_bf16<false, true, false><<<dim3(8, 64), 512, 0, stream>>>(
      att, 1024, wpT, 1024, bp, x, x2, 1024, 1024);
  // 5) h2b = LN(x2)
  ln_kernel<<<dim3(Mrows), 256, 0, stream>>>(x2, g2, be2, h1b);
  // 6) ffh = relu(h2b @ w1 + b1)  (256^2 4-phase — grid 16x32)
  gemm256_relu<<<dim3(16, 32), 512, 0, stream>>>(h1b, w1T, b1, ffh, 4096);
  // 7) out = x2 + ffh @ w2 + b2  (128^2 ring)
  gemm_bf16<false, true, false><<<dim3(8, 64), 512, 0, stream>>>(
      ffh, 4096, w2T, 4096, b2, x2, out, 1024, 4096);
}